// Round 5
// baseline (548.283 us; speedup 1.0000x reference)
//
#include <hip/hip_runtime.h>
#include <hip/hip_bf16.h>

// ---------- helpers ----------
__device__ __forceinline__ float bf2f(unsigned short u) {
    union { unsigned int i; float f; } x;
    x.i = ((unsigned int)u) << 16;
    return x.f;
}
__device__ __forceinline__ unsigned short f2bf(float f) {
    union { float f; unsigned int u; } x; x.f = f;
    unsigned int r = x.u + 0x7FFFu + ((x.u >> 16) & 1u);
    return (unsigned short)(r >> 16);
}
__device__ __forceinline__ float fast_tanh(float x) {
    float a = fabsf(x);
    float t = __expf(2.f * a);
    float r = 1.f - 2.f / (t + 1.f);
    return copysignf(r, x);
}

typedef __bf16    bf16x8 __attribute__((ext_vector_type(8)));
typedef _Float16  f16x8  __attribute__((ext_vector_type(8)));
typedef _Float16  f16x4  __attribute__((ext_vector_type(4)));
typedef float     f32x4  __attribute__((ext_vector_type(4)));

// ---------- workspace byte offsets (total ~110.5 MB) ----------
#define XW_OFF     0UL            // N*256 bf16      = 25,600,000
#define ZB_OFF     25600000UL     // 3N*256 f16      = 76,800,000 (bias folded)
                                  // (packed-edge scratch reuses this region
                                  //  before agg_csr writes zb)
#define CSR_OFF    102400000UL    // 3E u16          =  2,400,000
#define RS_OFF     107200000UL    // (3N+1) int32
#define CUR_OFF    107800064UL    // 3N int32
#define BS_OFF     108400128UL    // 256 int32
#define AS_OFF     108401152UL    // N*4 f32
#define AD_OFF     109201152UL    // N*4 f32
#define WT_OFF     110001152UL    // 3*256*256 bf16 (transposed W)
#define W1T_OFF    110394368UL    // 128*256 f16 (transposed w1)
#define ASF_OFF    110459904UL    // 768 f32
#define ADF_OFF    110462976UL
#define BIASF_OFF  110466048UL
#define B1F_OFF    110469120UL
#define W2F_OFF    110469632UL
#define WSUM_OFF   110470144UL
#define BETA_OFF   110470208UL
#define FLAG_OFF   110470272UL

// ---------- P0: dtype probe ----------
__global__ void probe(const unsigned short* __restrict__ hraw,
                      const unsigned int* __restrict__ eraw,
                      int* __restrict__ flags) {
    if (threadIdx.x == 0 && blockIdx.x == 0) {
        int sane = 0;
        for (int i = 0; i < 256; ++i) {
            unsigned int e = (hraw[i] >> 7) & 0xFF;
            if (hraw[i] != 0 && e >= 100 && e <= 150) sane++;
        }
        flags[0] = (sane >= 220) ? 1 : 0;   // 1 = bf16 inputs/outputs
        int zeros = 0;
        for (int i = 1; i < 256; i += 2) if (eraw[i] == 0u) zeros++;
        flags[1] = (zeros >= 120) ? 1 : 0;  // 1 = int64 indices
    }
}

__device__ __forceinline__ float rd_f(const void* p, int j, bool bf) {
    return bf ? bf2f(((const unsigned short*)p)[j]) : ((const float*)p)[j];
}
__device__ __forceinline__ int rd_i(const void* p, long long j, bool i64) {
    return i64 ? (int)((const long long*)p)[j] : ((const int*)p)[j];
}

// ---------- P1: canonicalize params ----------
__global__ void ingest_params(const void* W, const void* as, const void* ad, const void* bias,
                              const void* w1, const void* b1, const void* w2,
                              unsigned short* Wt, _Float16* w1t,
                              float* asf, float* adf, float* biasf,
                              float* b1f, float* w2f,
                              const int* __restrict__ flags) {
    int i = blockIdx.x * 256 + threadIdx.x;
    bool bf = flags[0] != 0;
    if (i < 196608) {                              // Wt[p][n][k] = W[p][k][n]
        int p = i >> 16, n = (i >> 8) & 255, k = i & 255;
        Wt[i] = f2bf(rd_f(W, p * 65536 + k * 256 + n, bf));
    } else if (i < 229376) {                       // w1t[n][k] = w1[k][n], fp16
        int j = i - 196608;
        int n = j >> 8, k = j & 255;
        w1t[j] = (_Float16)rd_f(w1, k * 128 + n, bf);
    } else if (i < 230144) {
        int j = i - 229376; asf[j] = rd_f(as, j, bf);
    } else if (i < 230912) {
        int j = i - 230144; adf[j] = rd_f(ad, j, bf);
    } else if (i < 231680) {
        int j = i - 230912; biasf[j] = rd_f(bias, j, bf);
    } else if (i < 231808) {
        int j = i - 231680; b1f[j] = rd_f(b1, j, bf);
    } else if (i < 231936) {
        int j = i - 231808; w2f[j] = rd_f(w2, j, bf);
    }
}

// ---------- CSR build v3: pack edges u32 + hist in one pass, u16 csr ----------
// conv_hist: read int64 edges once, emit packed (src | dst<<16), histogram cur.
// 4 edges/thread (independent chains -> 4x memory-level parallelism).
// NOTE: i >= T4 guard is essential — extra threads would duplicate edges.
__global__ void conv_hist(const void* e0, const void* e1, const void* e2,
                          unsigned int* __restrict__ ed, int* __restrict__ cur,
                          int E, int N, int T4, const int* __restrict__ flags) {
    int i = blockIdx.x * 256 + threadIdx.x;
    if (i >= T4) return;
    bool i64 = flags[1] != 0;
    int tot = 3 * E;
#pragma unroll
    for (int c = 0; c < 4; ++c) {
        int idx = i + c * T4;
        if (idx >= tot) continue;
        int p = idx / E, e = idx - p * E;
        const void* ep = (p == 0) ? e0 : (p == 1) ? e1 : e2;
        unsigned int src = (unsigned int)rd_i(ep, e, i64);
        unsigned int dst = (unsigned int)rd_i(ep, (long long)E + e, i64);
        ed[idx] = src | (dst << 16);
        atomicAdd(&cur[p * N + (int)dst], 1);
    }
}

__global__ void scan1(const int* __restrict__ cnt, int* __restrict__ rs,
                      int* __restrict__ bs, int M) {
    __shared__ int s[1024];
    int t = threadIdx.x, i = blockIdx.x * 1024 + t;
    int v = (i < M) ? cnt[i] : 0;
    s[t] = v; __syncthreads();
    for (int o = 1; o < 1024; o <<= 1) {
        int tmp = (t >= o) ? s[t - o] : 0;
        __syncthreads();
        s[t] += tmp;
        __syncthreads();
    }
    if (i < M) rs[i] = s[t] - v;
    if (t == 1023) bs[blockIdx.x] = s[t];
}

__global__ void scan2(int* __restrict__ bs, int* __restrict__ rs, int nb, int M) {
    __shared__ int s[256];
    int t = threadIdx.x;
    int v = (t < nb) ? bs[t] : 0;
    s[t] = v; __syncthreads();
    for (int o = 1; o < 256; o <<= 1) {
        int tmp = (t >= o) ? s[t - o] : 0;
        __syncthreads();
        s[t] += tmp;
        __syncthreads();
    }
    if (t < nb) bs[t] = s[t] - v;
    if (t == nb - 1) rs[M] = s[t];
}

__global__ void scan3(int* __restrict__ rs, const int* __restrict__ bs, int M) {
    int i = blockIdx.x * 1024 + threadIdx.x;
    if (i < M) rs[i] += bs[blockIdx.x];
}

// scatter: packed edges (coalesced u32 reads) -> u16 csr, 4 edges/thread
__global__ void scatter(const unsigned int* __restrict__ ed,
                        const int* __restrict__ rs, int* __restrict__ cur,
                        unsigned short* __restrict__ csr, int E, int N, int T4) {
    int i = blockIdx.x * 256 + threadIdx.x;
    if (i >= T4) return;
    int tot = 3 * E;
#pragma unroll
    for (int c = 0; c < 4; ++c) {
        int idx = i + c * T4;
        if (idx >= tot) continue;
        unsigned int u = ed[idx];
        int p = idx / E;
        int seg = p * N + (int)(u >> 16);
        int pos = rs[seg] + atomicAdd(&cur[seg], 1);
        csr[pos] = (unsigned short)(u & 0xFFFFu);
    }
}

// ---------- K1: xw = h @ W[p] (MFMA, B in swizzled LDS, wave = 64r x 128c) ----------
__global__ __launch_bounds__(256, 2)
void gemm_xw_mfma(const void* __restrict__ h,
                  const unsigned short* __restrict__ Wtp,   // [256 n][256 k] bf16
                  unsigned short* __restrict__ xw,
                  const float* __restrict__ asf,            // [256] this path
                  const float* __restrict__ adf,
                  float* __restrict__ as_, float* __restrict__ ad_,
                  const int* __restrict__ flags, int N) {
    __shared__ __bf16 Bs[32768];        // 64 KB: 128 rows x 256 k, 16B-chunk XOR swizzle
    int tid  = threadIdx.x;
    int ch   = blockIdx.x & 1;          // col half
    int rg   = blockIdx.x >> 1;         // row group (256 rows)
    // stage B half into LDS (chunk c of row r -> slot c ^ (r&7))
    {
        const bf16x8* src = (const bf16x8*)Wtp;
#pragma unroll
        for (int it = 0; it < 16; ++it) {
            int c = it * 256 + tid;
            int row = c >> 5, cv = c & 31;
            *(bf16x8*)(Bs + ((row << 5) + (cv ^ (row & 7))) * 8) =
                src[(ch * 128 + row) * 32 + cv];
        }
    }
    __syncthreads();

    int wave = tid >> 6, lane = tid & 63;
    int l15 = lane & 15, quad = lane >> 4;
    int sw  = l15 & 7;
    int row0 = rg * 256 + wave * 64;
    bool bfm = flags[0] != 0;

    int lr[4];
#pragma unroll
    for (int rt = 0; rt < 4; ++rt) lr[rt] = min(row0 + rt * 16 + l15, N - 1);

    f32x4 acc[4][8];
#pragma unroll
    for (int rt = 0; rt < 4; ++rt)
#pragma unroll
        for (int tn = 0; tn < 8; ++tn) acc[rt][tn] = (f32x4){0.f, 0.f, 0.f, 0.f};

#pragma unroll
    for (int c0 = 0; c0 < 32; c0 += 4) {          // k chunk base (16B units), k = c0*8
        int kc = c0 * 8;
        bf16x8 a[4];
#pragma unroll
        for (int rt = 0; rt < 4; ++rt) {
            size_t off = (size_t)lr[rt] * 256 + kc + quad * 8;
            if (bfm) {
                a[rt] = *reinterpret_cast<const bf16x8*>((const __bf16*)h + off);
            } else {
                f32x4 u0 = *reinterpret_cast<const f32x4*>((const float*)h + off);
                f32x4 u1 = *reinterpret_cast<const f32x4*>((const float*)h + off + 4);
#pragma unroll
                for (int j = 0; j < 4; ++j) { a[rt][j] = (__bf16)u0[j]; a[rt][4 + j] = (__bf16)u1[j]; }
            }
        }
#pragma unroll
        for (int tn = 0; tn < 8; ++tn) {
            int row = tn * 16 + l15;
            bf16x8 b = *reinterpret_cast<const bf16x8*>(
                Bs + ((row << 5) + (((c0 + quad)) ^ sw)) * 8);
#pragma unroll
            for (int rt = 0; rt < 4; ++rt)
                acc[rt][tn] = __builtin_amdgcn_mfma_f32_16x16x32_bf16(a[rt], b, acc[rt][tn], 0, 0, 0);
        }
    }

    // epilogue: store xw + fused alpha (wave owns heads {2ch, 2ch+1})
#pragma unroll
    for (int rt = 0; rt < 4; ++rt) {
        int rbase = row0 + rt * 16 + quad * 4;
#pragma unroll
        for (int tn = 0; tn < 8; ++tn) {
            int c = ch * 128 + tn * 16 + l15;
#pragma unroll
            for (int i = 0; i < 4; ++i) {
                int r = rbase + i;
                if (r < N) xw[(size_t)r * 256 + c] = f2bf(acc[rt][tn][i]);
            }
        }
        float ss[2][4] = {{0.f,0.f,0.f,0.f},{0.f,0.f,0.f,0.f}};
        float dd[2][4] = {{0.f,0.f,0.f,0.f},{0.f,0.f,0.f,0.f}};
#pragma unroll
        for (int tn = 0; tn < 8; ++tn) {
            int c = ch * 128 + tn * 16 + l15;
            float sv = asf[c], dv = adf[c];
            int hs = tn >> 2;
#pragma unroll
            for (int i = 0; i < 4; ++i) {
                ss[hs][i] += acc[rt][tn][i] * sv;
                dd[hs][i] += acc[rt][tn][i] * dv;
            }
        }
#pragma unroll
        for (int hs = 0; hs < 2; ++hs)
#pragma unroll
            for (int i = 0; i < 4; ++i) {
                float s = ss[hs][i], d = dd[hs][i];
                s += __shfl_xor(s, 1); d += __shfl_xor(d, 1);
                s += __shfl_xor(s, 2); d += __shfl_xor(d, 2);
                s += __shfl_xor(s, 4); d += __shfl_xor(d, 4);
                s += __shfl_xor(s, 8); d += __shfl_xor(d, 8);
                ss[hs][i] = s; dd[hs][i] = d;
            }
        if (l15 == 0) {
#pragma unroll
            for (int hs = 0; hs < 2; ++hs)
#pragma unroll
                for (int i = 0; i < 4; ++i) {
                    int r = rbase + i;
                    if (r < N) {
                        int g = r * 4 + ch * 2 + hs;
                        as_[g] = ss[hs][i];
                        ad_[g] = dd[hs][i];
                    }
                }
        }
    }
}

__device__ __forceinline__ float leaky(float v) { return v > 0.f ? v : 0.2f * v; }

// ---------- K5: CSR online-softmax aggregate -> z' fp16 (bias folded) ----------
// 4-wide chunked online softmax: 4 score + 4 row loads in flight per step
// (L3-latency hiding), merged state update once per chunk (associative).
__global__ void agg_csr(const unsigned short* __restrict__ csr, const int* __restrict__ rs,
                        const float* __restrict__ as_, const float* __restrict__ ad_,
                        const unsigned short* __restrict__ xw,
                        const float* __restrict__ biasf,
                        _Float16* __restrict__ zb, int N, int p) {
    int d = blockIdx.x * 4 + (threadIdx.x >> 6);
    if (d >= N) return;
    int lane = threadIdx.x & 63;
    int h = lane >> 4;
    int seg = p * N + d;
    int start = rs[seg], end = rs[seg + 1];

    float adh = ad_[d * 4 + h];
    float m = leaky(as_[d * 4 + h] + adh);
    float l = 1.f;
    float a0, a1, a2, a3;
    {
        ushort4 u = *reinterpret_cast<const ushort4*>(xw + (size_t)d * 256 + lane * 4);
        a0 = bf2f(u.x); a1 = bf2f(u.y); a2 = bf2f(u.z); a3 = bf2f(u.w);
    }
    for (int j = start; j < end; j += 4) {
        // gather 4 neighbors (tail: clamp src, score -> -1e30 => weight 0)
        int s0 = csr[j];
        int s1 = (j + 1 < end) ? csr[j + 1] : s0;
        int s2 = (j + 2 < end) ? csr[j + 2] : s0;
        int s3 = (j + 3 < end) ? csr[j + 3] : s0;
        float e0 = leaky(as_[s0 * 4 + h] + adh);
        float e1 = (j + 1 < end) ? leaky(as_[s1 * 4 + h] + adh) : -1e30f;
        float e2 = (j + 2 < end) ? leaky(as_[s2 * 4 + h] + adh) : -1e30f;
        float e3 = (j + 3 < end) ? leaky(as_[s3 * 4 + h] + adh) : -1e30f;
        ushort4 u0 = *reinterpret_cast<const ushort4*>(xw + (size_t)s0 * 256 + lane * 4);
        ushort4 u1 = *reinterpret_cast<const ushort4*>(xw + (size_t)s1 * 256 + lane * 4);
        ushort4 u2 = *reinterpret_cast<const ushort4*>(xw + (size_t)s2 * 256 + lane * 4);
        ushort4 u3 = *reinterpret_cast<const ushort4*>(xw + (size_t)s3 * 256 + lane * 4);

        float mn = fmaxf(fmaxf(fmaxf(m, e0), fmaxf(e1, e2)), e3);
        float c  = __expf(m - mn);
        float w0 = __expf(e0 - mn);
        float w1 = __expf(e1 - mn);
        float w2 = __expf(e2 - mn);
        float w3 = __expf(e3 - mn);
        m = mn;
        l = l * c + w0 + w1 + w2 + w3;
        a0 = a0 * c + w0 * bf2f(u0.x) + w1 * bf2f(u1.x) + w2 * bf2f(u2.x) + w3 * bf2f(u3.x);
        a1 = a1 * c + w0 * bf2f(u0.y) + w1 * bf2f(u1.y) + w2 * bf2f(u2.y) + w3 * bf2f(u3.y);
        a2 = a2 * c + w0 * bf2f(u0.z) + w1 * bf2f(u1.z) + w2 * bf2f(u2.z) + w3 * bf2f(u3.z);
        a3 = a3 * c + w0 * bf2f(u0.w) + w1 * bf2f(u1.w) + w2 * bf2f(u2.w) + w3 * bf2f(u3.w);
    }
    float inv = 1.f / l;
    int col = lane * 4;
    const float* bp = biasf + p * 256 + col;
    f16x4 o = {(_Float16)(a0 * inv + bp[0]), (_Float16)(a1 * inv + bp[1]),
               (_Float16)(a2 * inv + bp[2]), (_Float16)(a3 * inv + bp[3])};
    *reinterpret_cast<f16x4*>(zb + ((size_t)d * 3 + p) * 256 + col) = o;
}

// ---------- K6: semantic attention (f16 MFMA, w1 in swizzled LDS) ----------
// 1024-thread blocks (16 waves, 16 rows/wave): 64 KB w1 tile serves 16 waves,
// 2 blocks/CU -> 32 waves/CU.
__global__ __launch_bounds__(1024, 4)
void sem_w_mfma(const _Float16* __restrict__ zb,
                const _Float16* __restrict__ w1t,   // [128 n][256 k] f16
                const float* __restrict__ b1f,
                const float* __restrict__ w2f,
                float* __restrict__ wsum, int rows) {
    __shared__ _Float16 Bs[32768];      // 64 KB, 16B-chunk XOR swizzle
    __shared__ float redbuf[16][3];     // per-wave bins for block reduction
    int tid = threadIdx.x;
    {
        const f16x8* src = (const f16x8*)w1t;
#pragma unroll
        for (int it = 0; it < 4; ++it) {
            int c = it * 1024 + tid;
            int row = c >> 5, cv = c & 31;
            *(f16x8*)(Bs + ((row << 5) + (cv ^ (row & 7))) * 8) = src[c];
        }
    }
    __syncthreads();

    int wave = tid >> 6, lane = tid & 63;
    int l15 = lane & 15, quad = lane >> 4;
    int sw  = l15 & 7;
    int row0 = blockIdx.x * 256 + wave * 16;
    int lr = min(row0 + l15, rows - 1);

    f32x4 acc[8];
#pragma unroll
    for (int tn = 0; tn < 8; ++tn) acc[tn] = (f32x4){0.f, 0.f, 0.f, 0.f};

#pragma unroll
    for (int c0 = 0; c0 < 32; c0 += 4) {
        int kc = c0 * 8;
        f16x8 a = *reinterpret_cast<const f16x8*>(zb + (size_t)lr * 256 + kc + quad * 8);
#pragma unroll
        for (int tn = 0; tn < 8; ++tn) {
            int brow = tn * 16 + l15;
            f16x8 b = *reinterpret_cast<const f16x8*>(
                Bs + ((brow << 5) + ((c0 + quad) ^ sw)) * 8);
            acc[tn] = __builtin_amdgcn_mfma_f32_16x16x32_f16(a, b, acc[tn], 0, 0, 0);
        }
    }

    // epilogue: per-row tanh-dot, reduce over hidden (l15), bin by row%3
    float rowsum[4] = {0.f, 0.f, 0.f, 0.f};
#pragma unroll
    for (int tn = 0; tn < 8; ++tn) {
        int col = tn * 16 + l15;
        float b1v = b1f[col], w2v = w2f[col];
#pragma unroll
        for (int i = 0; i < 4; ++i)
            rowsum[i] += fast_tanh(acc[tn][i] + b1v) * w2v;
    }
#pragma unroll
    for (int i = 0; i < 4; ++i) {
        rowsum[i] += __shfl_xor(rowsum[i], 1);
        rowsum[i] += __shfl_xor(rowsum[i], 2);
        rowsum[i] += __shfl_xor(rowsum[i], 4);
        rowsum[i] += __shfl_xor(rowsum[i], 8);
    }
    float bins[3] = {0.f, 0.f, 0.f};
    if (l15 == 0) {
#pragma unroll
        for (int i = 0; i < 4; ++i) {
            int r = row0 + quad * 4 + i;
            if (r < rows) bins[r % 3] += rowsum[i];
        }
    }
#pragma unroll
    for (int b = 0; b < 3; ++b) {   // combine the 4 quads (lanes 0,16,32,48)
        bins[b] += __shfl_xor(bins[b], 16);
        bins[b] += __shfl_xor(bins[b], 32);
    }
    if (lane == 0) {
#pragma unroll
        for (int b = 0; b < 3; ++b) redbuf[wave][b] = bins[b];
    }
    __syncthreads();
    if (tid < 3) {                  // block-level reduce: 3 atomics per block
        float s = 0.f;
#pragma unroll
        for (int w = 0; w < 16; ++w) s += redbuf[w][tid];
        atomicAdd(&wsum[tid], s);
    }
}

// ---------- K8: combine with fused beta = softmax(mean) ----------
__global__ void combine(const _Float16* __restrict__ zb,
                        const float* __restrict__ wsum, float invN,
                        void* __restrict__ out, const int* __restrict__ flags) {
    int idx = blockIdx.x * 256 + threadIdx.x;    // over N*64
    int n = idx >> 6, c4 = (idx & 63) * 4;
    float w0 = wsum[0] * invN, w1 = wsum[1] * invN, w2 = wsum[2] * invN;
    float mx = fmaxf(w0, fmaxf(w1, w2));
    float e0 = __expf(w0 - mx), e1 = __expf(w1 - mx), e2 = __expf(w2 - mx);
    float s = 1.f / (e0 + e1 + e2);
    float b0 = e0 * s, b1 = e1 * s, b2 = e2 * s;
    const _Float16* base = zb + (size_t)n * 768 + c4;
    f16x4 z0 = *reinterpret_cast<const f16x4*>(base);
    f16x4 z1 = *reinterpret_cast<const f16x4*>(base + 256);
    f16x4 z2 = *reinterpret_cast<const f16x4*>(base + 512);
    float v[4];
#pragma unroll
    for (int i = 0; i < 4; ++i)
        v[i] = b0 * (float)z0[i] + b1 * (float)z1[i] + b2 * (float)z2[i];
    if (flags[0]) {
        ushort4 o = {f2bf(v[0]), f2bf(v[1]), f2bf(v[2]), f2bf(v[3])};
        *reinterpret_cast<ushort4*>((unsigned short*)out + (size_t)idx * 4) = o;
    } else {
        f32x4 o = {v[0], v[1], v[2], v[3]};
        *reinterpret_cast<f32x4*>((float*)out + (size_t)idx * 4) = o;
    }
}

extern "C" void kernel_launch(void* const* d_in, const int* in_sizes, int n_in,
                              void* d_out, int out_size, void* d_ws, size_t ws_size,
                              hipStream_t stream) {
    const void* h    = d_in[0];
    const void* e0   = d_in[1];
    const void* e1   = d_in[2];
    const void* e2   = d_in[3];
    const void* W    = d_in[4];
    const void* as   = d_in[5];
    const void* ad   = d_in[6];
    const void* bias = d_in[7];
    const void* w1   = d_in[8];
    const void* b1   = d_in[9];
    const void* w2   = d_in[10];

    const int N = in_sizes[0] / 256;   // 50000
    const int E = in_sizes[1] / 2;     // 400000
    const int M = 3 * N;               // 150000 segments
    const int T4 = (3 * E + 3) / 4;    // edges per strided chunk

    char* ws = (char*)d_ws;
    unsigned short* xw    = (unsigned short*)(ws + XW_OFF);
    _Float16*       zb    = (_Float16*)(ws + ZB_OFF);
    unsigned short* csr   = (unsigned short*)(ws + CSR_OFF);
    int*            rs    = (int*)(ws + RS_OFF);
    int*            cur   = (int*)(ws + CUR_OFF);
    int*            bs    = (int*)(ws + BS_OFF);
    float*          as_   = (float*)(ws + AS_OFF);
    float*          ad_   = (float*)(ws + AD_OFF);
    unsigned short* Wt    = (unsigned short*)(ws + WT_OFF);
    _Float16*       w1t   = (_Float16*)(ws + W1T_OFF);
    float*          asf   = (float*)(ws + ASF_OFF);
    float*          adf   = (float*)(ws + ADF_OFF);
    float*          biasf = (float*)(ws + BIASF_OFF);
    float*          b1f   = (float*)(ws + B1F_OFF);
    float*          w2f   = (float*)(ws + W2F_OFF);
    float*          wsum  = (float*)(ws + WSUM_OFF);
    int*            flags = (int*)(ws + FLAG_OFF);

    // packed-edge scratch overlays the zb region (dead until agg_csr)
    unsigned int* ed = (unsigned int*)(ws + ZB_OFF);   // 3E u32 = 4.8 MB

    probe<<<1, 64, 0, stream>>>((const unsigned short*)h, (const unsigned int*)e0, flags);
    ingest_params<<<907, 256, 0, stream>>>(W, as, ad, bias, w1, b1, w2,
                                           Wt, w1t, asf, adf, biasf, b1f, w2f, flags);

    // CSR build v3
    int nb = (M + 1023) / 1024;                    // 147
    int e4B = (T4 + 255) / 256;                    // 1172
    hipMemsetAsync(cur, 0, M * sizeof(int), stream);
    conv_hist<<<e4B, 256, 0, stream>>>(e0, e1, e2, ed, cur, E, N, T4, flags);
    scan1<<<nb, 1024, 0, stream>>>(cur, rs, bs, M);
    scan2<<<1, 256, 0, stream>>>(bs, rs, nb, M);
    scan3<<<nb, 1024, 0, stream>>>(rs, bs, M);
    hipMemsetAsync(cur, 0, M * sizeof(int), stream);
    scatter<<<e4B, 256, 0, stream>>>(ed, rs, cur, csr, E, N, T4);

    hipMemsetAsync(wsum, 0, 16, stream);

    int gemmBlocks = ((N + 255) / 256) * 2;        // 392
    int aggBlocks  = (N + 3) / 4;                  // 12500
    for (int p = 0; p < 3; ++p) {
        gemm_xw_mfma<<<gemmBlocks, 256, 0, stream>>>(h, Wt + p * 65536, xw,
                                                     asf + p * 256, adf + p * 256,
                                                     as_, ad_, flags, N);
        agg_csr<<<aggBlocks, 256, 0, stream>>>(csr, rs, as_, ad_, xw, biasf, zb, N, p);
    }

    int semBlocks = (M + 255) / 256;               // 586
    sem_w_mfma<<<semBlocks, 1024, 0, stream>>>(zb, w1t, b1f, w2f, wsum, M);
    combine<<<(N * 64 + 255) / 256, 256, 0, stream>>>(zb, wsum, 1.0f / (float)N, d_out, flags);
}

// Round 6
// 455.791 us; speedup vs baseline: 1.2029x; 1.2029x over previous
//
#include <hip/hip_runtime.h>
#include <hip/hip_bf16.h>

// ---------- helpers ----------
__device__ __forceinline__ float bf2f(unsigned short u) {
    union { unsigned int i; float f; } x;
    x.i = ((unsigned int)u) << 16;
    return x.f;
}
__device__ __forceinline__ unsigned short f2bf(float f) {
    union { float f; unsigned int u; } x; x.f = f;
    unsigned int r = x.u + 0x7FFFu + ((x.u >> 16) & 1u);
    return (unsigned short)(r >> 16);
}
__device__ __forceinline__ float fast_tanh(float x) {
    float a = fabsf(x);
    float t = __expf(2.f * a);
    float r = 1.f - 2.f / (t + 1.f);
    return copysignf(r, x);
}

typedef __bf16    bf16x8 __attribute__((ext_vector_type(8)));
typedef _Float16  f16x8  __attribute__((ext_vector_type(8)));
typedef _Float16  f16x4  __attribute__((ext_vector_type(4)));
typedef float     f32x4  __attribute__((ext_vector_type(4)));

// ---------- workspace byte offsets (total ~110.5 MB) ----------
#define XW_OFF     0UL            // N*256 bf16      = 25,600,000
#define ZB_OFF     25600000UL     // 3N*256 f16      = 76,800,000 (bias folded)
                                  // (bucket-sort scratch reuses this region
                                  //  before agg_csr writes zb)
#define CSR_OFF    102400000UL    // 3E u16          =  2,400,000
#define RS_OFF     107200000UL    // (3N+1) int32
#define CUR_OFF    107800064UL    // 3N int32 (unused now)
#define BS_OFF     108400128UL    // 256 int32 (unused now)
#define AS_OFF     108401152UL    // N*4 f32
#define AD_OFF     109201152UL    // N*4 f32
#define WT_OFF     110001152UL    // 3*256*256 bf16 (transposed W)
#define W1T_OFF    110394368UL    // 128*256 f16 (transposed w1)
#define ASF_OFF    110459904UL    // 768 f32
#define ADF_OFF    110462976UL
#define BIASF_OFF  110466048UL
#define B1F_OFF    110469120UL
#define W2F_OFF    110469632UL
#define WSUM_OFF   110470144UL
#define BETA_OFF   110470208UL
#define FLAG_OFF   110470272UL

// ---------- CSR-build v4 constants ----------
#define CHUNKA 5000     // edges per bucket_a block
#define NBMAX  152      // >= NB = ceil(3N/1024) = 147 ; must be <= 255 (u8)
#define CAPB   16384    // per-bucket capacity (mean 8163, +90 sigma)

// ---------- P0: dtype probe ----------
__global__ void probe(const unsigned short* __restrict__ hraw,
                      const unsigned int* __restrict__ eraw,
                      int* __restrict__ flags) {
    if (threadIdx.x == 0 && blockIdx.x == 0) {
        int sane = 0;
        for (int i = 0; i < 256; ++i) {
            unsigned int e = (hraw[i] >> 7) & 0xFF;
            if (hraw[i] != 0 && e >= 100 && e <= 150) sane++;
        }
        flags[0] = (sane >= 220) ? 1 : 0;   // 1 = bf16 inputs/outputs
        int zeros = 0;
        for (int i = 1; i < 256; i += 2) if (eraw[i] == 0u) zeros++;
        flags[1] = (zeros >= 120) ? 1 : 0;  // 1 = int64 indices
    }
}

__device__ __forceinline__ float rd_f(const void* p, int j, bool bf) {
    return bf ? bf2f(((const unsigned short*)p)[j]) : ((const float*)p)[j];
}
__device__ __forceinline__ int rd_i(const void* p, long long j, bool i64) {
    return i64 ? (int)((const long long*)p)[j] : ((const int*)p)[j];
}

// ---------- P1: canonicalize params ----------
__global__ void ingest_params(const void* W, const void* as, const void* ad, const void* bias,
                              const void* w1, const void* b1, const void* w2,
                              unsigned short* Wt, _Float16* w1t,
                              float* asf, float* adf, float* biasf,
                              float* b1f, float* w2f,
                              const int* __restrict__ flags) {
    int i = blockIdx.x * 256 + threadIdx.x;
    bool bf = flags[0] != 0;
    if (i < 196608) {                              // Wt[p][n][k] = W[p][k][n]
        int p = i >> 16, n = (i >> 8) & 255, k = i & 255;
        Wt[i] = f2bf(rd_f(W, p * 65536 + k * 256 + n, bf));
    } else if (i < 229376) {                       // w1t[n][k] = w1[k][n], fp16
        int j = i - 196608;
        int n = j >> 8, k = j & 255;
        w1t[j] = (_Float16)rd_f(w1, k * 128 + n, bf);
    } else if (i < 230144) {
        int j = i - 229376; asf[j] = rd_f(as, j, bf);
    } else if (i < 230912) {
        int j = i - 230144; adf[j] = rd_f(ad, j, bf);
    } else if (i < 231680) {
        int j = i - 230912; biasf[j] = rd_f(bias, j, bf);
    } else if (i < 231808) {
        int j = i - 231680; b1f[j] = rd_f(b1, j, bf);
    } else if (i < 231936) {
        int j = i - 231808; w2f[j] = rd_f(w2, j, bf);
    }
}

// ---------- CSR build v4: LDS-staged two-pass counting sort ----------
// bucket = seg >> 10 (1024 segments/bucket, NB = 147 buckets).
// bucket_a: each block sorts its 5000-edge chunk by bucket in LDS, reserves
// per-(block,bucket) ranges with ONE global atomic each, writes runs coalesced.
__global__ __launch_bounds__(256)
void bucket_a(const void* e0, const void* e1, const void* e2,
              int* __restrict__ bcnt, unsigned int* __restrict__ bkt,
              int E, int N, int NB, const int* __restrict__ flags) {
    __shared__ unsigned int  ent[CHUNKA];
    __shared__ unsigned char bck[CHUNKA];
    __shared__ unsigned int  sent[CHUNKA];
    __shared__ unsigned char sbck[CHUNKA];
    __shared__ int lcnt[NBMAX], lpre[NBMAX], lbase[NBMAX], lcur[NBMAX];
    int tid = threadIdx.x;
    int s = blockIdx.x * CHUNKA;
    int tot = 3 * E;
    int n = min(tot, s + CHUNKA) - s;
    for (int b = tid; b < NBMAX; b += 256) { lcnt[b] = 0; lcur[b] = 0; }
    __syncthreads();
    bool i64 = flags[1] != 0;
    for (int i = tid; i < n; i += 256) {
        int idx = s + i;
        int p = (idx >= 2 * E) ? 2 : (idx >= E) ? 1 : 0;
        int j = idx - p * E;
        const void* ep = (p == 0) ? e0 : (p == 1) ? e1 : e2;
        unsigned int src = (unsigned int)rd_i(ep, j, i64);
        unsigned int dst = (unsigned int)rd_i(ep, (long long)E + j, i64);
        int seg = p * N + (int)dst;
        int b = seg >> 10;
        ent[i] = src | ((unsigned int)(seg & 1023) << 16);
        bck[i] = (unsigned char)b;
        atomicAdd(&lcnt[b], 1);
    }
    __syncthreads();
    if (tid == 0) {                       // block-local exclusive prefix (147 iters)
        int run = 0;
        for (int b = 0; b < NB; ++b) { lpre[b] = run; run += lcnt[b]; }
    }
    if (tid < NB) lbase[tid] = atomicAdd(&bcnt[tid], lcnt[tid]);   // global reserve
    __syncthreads();
    for (int i = tid; i < n; i += 256) {  // LDS counting-sort placement
        int b = bck[i];
        int pos = lpre[b] + atomicAdd(&lcur[b], 1);
        sent[pos] = ent[i];
        sbck[pos] = (unsigned char)b;
    }
    __syncthreads();
    for (int q = tid; q < n; q += 256) {  // coalesced run write-out
        int b = sbck[q];
        int gpos = lbase[b] + (q - lpre[b]);
        if (gpos < CAPB) bkt[(size_t)b * CAPB + gpos] = sent[q];
    }
}

// bucket_b: per bucket, LDS per-seg histogram + prefix -> writes rs directly
// and places edges into its contiguous csr region (full-line writebacks).
__global__ __launch_bounds__(256)
void bucket_b(const int* __restrict__ bcnt, const unsigned int* __restrict__ bkt,
              int* __restrict__ rs, unsigned short* __restrict__ csr,
              int M, int NB, int tot) {
    __shared__ int scnt[1024];
    __shared__ int spre[1024];
    __shared__ int part[256];
    int b = blockIdx.x, tid = threadIdx.x;
    // base = prefix sum of bcnt[0..b)
    int acc = 0;
    for (int i = tid; i < b; i += 256) acc += min(bcnt[i], CAPB);
    part[tid] = acc; __syncthreads();
    for (int o = 128; o > 0; o >>= 1) {
        if (tid < o) part[tid] += part[tid + o];
        __syncthreads();
    }
    int base = part[0];
    int cnt = min(bcnt[b], CAPB);
    for (int i = tid; i < 1024; i += 256) scnt[i] = 0;
    __syncthreads();
    const unsigned int* src = bkt + (size_t)b * CAPB;
    for (int i = tid; i < cnt; i += 256)
        atomicAdd(&scnt[src[i] >> 16], 1);
    __syncthreads();
    // exclusive prefix over 1024 counters (4 items/thread + block scan)
    int a0 = scnt[tid * 4], a1 = scnt[tid * 4 + 1], a2 = scnt[tid * 4 + 2], a3 = scnt[tid * 4 + 3];
    int psum = a0 + a1 + a2 + a3;
    part[tid] = psum; __syncthreads();
    for (int o = 1; o < 256; o <<= 1) {
        int tmp = (tid >= o) ? part[tid - o] : 0;
        __syncthreads();
        part[tid] += tmp;
        __syncthreads();
    }
    int pb = part[tid] - psum;
    spre[tid * 4]     = pb;
    spre[tid * 4 + 1] = pb + a0;
    spre[tid * 4 + 2] = pb + a0 + a1;
    spre[tid * 4 + 3] = pb + a0 + a1 + a2;
    __syncthreads();
    // write rs for this bucket's segments; reset cursors
    for (int i = tid; i < 1024; i += 256) {
        int seg = b * 1024 + i;
        if (seg < M) rs[seg] = base + spre[i];
        scnt[i] = 0;
    }
    if (b == NB - 1 && tid == 0) rs[M] = tot;
    __syncthreads();
    // place (random within single-owner 16KB region -> full-line writebacks)
    for (int i = tid; i < cnt; i += 256) {
        unsigned int u = src[i];
        int slow = u >> 16;
        int pos = spre[slow] + atomicAdd(&scnt[slow], 1);
        csr[base + pos] = (unsigned short)(u & 0xFFFFu);
    }
}

// ---------- K1: xw = h @ W[p] (MFMA, B in swizzled LDS, wave = 64r x 128c) ----------
__global__ __launch_bounds__(256, 2)
void gemm_xw_mfma(const void* __restrict__ h,
                  const unsigned short* __restrict__ Wtp,   // [256 n][256 k] bf16
                  unsigned short* __restrict__ xw,
                  const float* __restrict__ asf,            // [256] this path
                  const float* __restrict__ adf,
                  float* __restrict__ as_, float* __restrict__ ad_,
                  const int* __restrict__ flags, int N) {
    __shared__ __bf16 Bs[32768];        // 64 KB: 128 rows x 256 k, 16B-chunk XOR swizzle
    int tid  = threadIdx.x;
    int ch   = blockIdx.x & 1;          // col half
    int rg   = blockIdx.x >> 1;         // row group (256 rows)
    // stage B half into LDS (chunk c of row r -> slot c ^ (r&7))
    {
        const bf16x8* src = (const bf16x8*)Wtp;
#pragma unroll
        for (int it = 0; it < 16; ++it) {
            int c = it * 256 + tid;
            int row = c >> 5, cv = c & 31;
            *(bf16x8*)(Bs + ((row << 5) + (cv ^ (row & 7))) * 8) =
                src[(ch * 128 + row) * 32 + cv];
        }
    }
    __syncthreads();

    int wave = tid >> 6, lane = tid & 63;
    int l15 = lane & 15, quad = lane >> 4;
    int sw  = l15 & 7;
    int row0 = rg * 256 + wave * 64;
    bool bfm = flags[0] != 0;

    int lr[4];
#pragma unroll
    for (int rt = 0; rt < 4; ++rt) lr[rt] = min(row0 + rt * 16 + l15, N - 1);

    f32x4 acc[4][8];
#pragma unroll
    for (int rt = 0; rt < 4; ++rt)
#pragma unroll
        for (int tn = 0; tn < 8; ++tn) acc[rt][tn] = (f32x4){0.f, 0.f, 0.f, 0.f};

#pragma unroll
    for (int c0 = 0; c0 < 32; c0 += 4) {          // k chunk base (16B units), k = c0*8
        int kc = c0 * 8;
        bf16x8 a[4];
#pragma unroll
        for (int rt = 0; rt < 4; ++rt) {
            size_t off = (size_t)lr[rt] * 256 + kc + quad * 8;
            if (bfm) {
                a[rt] = *reinterpret_cast<const bf16x8*>((const __bf16*)h + off);
            } else {
                f32x4 u0 = *reinterpret_cast<const f32x4*>((const float*)h + off);
                f32x4 u1 = *reinterpret_cast<const f32x4*>((const float*)h + off + 4);
#pragma unroll
                for (int j = 0; j < 4; ++j) { a[rt][j] = (__bf16)u0[j]; a[rt][4 + j] = (__bf16)u1[j]; }
            }
        }
#pragma unroll
        for (int tn = 0; tn < 8; ++tn) {
            int row = tn * 16 + l15;
            bf16x8 b = *reinterpret_cast<const bf16x8*>(
                Bs + ((row << 5) + (((c0 + quad)) ^ sw)) * 8);
#pragma unroll
            for (int rt = 0; rt < 4; ++rt)
                acc[rt][tn] = __builtin_amdgcn_mfma_f32_16x16x32_bf16(a[rt], b, acc[rt][tn], 0, 0, 0);
        }
    }

    // epilogue: store xw + fused alpha (wave owns heads {2ch, 2ch+1})
#pragma unroll
    for (int rt = 0; rt < 4; ++rt) {
        int rbase = row0 + rt * 16 + quad * 4;
#pragma unroll
        for (int tn = 0; tn < 8; ++tn) {
            int c = ch * 128 + tn * 16 + l15;
#pragma unroll
            for (int i = 0; i < 4; ++i) {
                int r = rbase + i;
                if (r < N) xw[(size_t)r * 256 + c] = f2bf(acc[rt][tn][i]);
            }
        }
        float ss[2][4] = {{0.f,0.f,0.f,0.f},{0.f,0.f,0.f,0.f}};
        float dd[2][4] = {{0.f,0.f,0.f,0.f},{0.f,0.f,0.f,0.f}};
#pragma unroll
        for (int tn = 0; tn < 8; ++tn) {
            int c = ch * 128 + tn * 16 + l15;
            float sv = asf[c], dv = adf[c];
            int hs = tn >> 2;
#pragma unroll
            for (int i = 0; i < 4; ++i) {
                ss[hs][i] += acc[rt][tn][i] * sv;
                dd[hs][i] += acc[rt][tn][i] * dv;
            }
        }
#pragma unroll
        for (int hs = 0; hs < 2; ++hs)
#pragma unroll
            for (int i = 0; i < 4; ++i) {
                float s = ss[hs][i], d = dd[hs][i];
                s += __shfl_xor(s, 1); d += __shfl_xor(d, 1);
                s += __shfl_xor(s, 2); d += __shfl_xor(d, 2);
                s += __shfl_xor(s, 4); d += __shfl_xor(d, 4);
                s += __shfl_xor(s, 8); d += __shfl_xor(d, 8);
                ss[hs][i] = s; dd[hs][i] = d;
            }
        if (l15 == 0) {
#pragma unroll
            for (int hs = 0; hs < 2; ++hs)
#pragma unroll
                for (int i = 0; i < 4; ++i) {
                    int r = rbase + i;
                    if (r < N) {
                        int g = r * 4 + ch * 2 + hs;
                        as_[g] = ss[hs][i];
                        ad_[g] = dd[hs][i];
                    }
                }
        }
    }
}

__device__ __forceinline__ float leaky(float v) { return v > 0.f ? v : 0.2f * v; }

// ---------- K5: CSR online-softmax aggregate -> z' fp16 (bias folded) ----------
// u16 csr; one-iteration software-pipeline lookahead on score + row loads.
__global__ void agg_csr(const unsigned short* __restrict__ csr, const int* __restrict__ rs,
                        const float* __restrict__ as_, const float* __restrict__ ad_,
                        const unsigned short* __restrict__ xw,
                        const float* __restrict__ biasf,
                        _Float16* __restrict__ zb, int N, int p) {
    int d = blockIdx.x * 4 + (threadIdx.x >> 6);
    if (d >= N) return;
    int lane = threadIdx.x & 63;
    int h = lane >> 4;
    int seg = p * N + d;
    int start = rs[seg], end = rs[seg + 1];

    float adh = ad_[d * 4 + h];
    float m = leaky(as_[d * 4 + h] + adh);
    float l = 1.f;
    float a0, a1, a2, a3;
    {
        ushort4 u = *reinterpret_cast<const ushort4*>(xw + (size_t)d * 256 + lane * 4);
        a0 = bf2f(u.x); a1 = bf2f(u.y); a2 = bf2f(u.z); a3 = bf2f(u.w);
    }
    if (start < end) {
        int srcA = csr[start];
        float sA = as_[srcA * 4 + h];
        ushort4 uA = *reinterpret_cast<const ushort4*>(xw + (size_t)srcA * 256 + lane * 4);
        for (int j = start; j < end; ++j) {
            // issue next-neighbor loads before this iteration's math
            int srcB = (j + 1 < end) ? csr[j + 1] : 0;
            float sB = as_[srcB * 4 + h];
            ushort4 uB = *reinterpret_cast<const ushort4*>(xw + (size_t)srcB * 256 + lane * 4);
            float v = leaky(sA + adh);
            float mn = fmaxf(m, v);
            float c = __expf(m - mn);
            float w = __expf(v - mn);
            m = mn;
            l = l * c + w;
            a0 = a0 * c + w * bf2f(uA.x);
            a1 = a1 * c + w * bf2f(uA.y);
            a2 = a2 * c + w * bf2f(uA.z);
            a3 = a3 * c + w * bf2f(uA.w);
            sA = sB; uA = uB;
        }
    }
    float inv = 1.f / l;
    int col = lane * 4;
    const float* bp = biasf + p * 256 + col;
    f16x4 o = {(_Float16)(a0 * inv + bp[0]), (_Float16)(a1 * inv + bp[1]),
               (_Float16)(a2 * inv + bp[2]), (_Float16)(a3 * inv + bp[3])};
    *reinterpret_cast<f16x4*>(zb + ((size_t)d * 3 + p) * 256 + col) = o;
}

// ---------- K6: semantic attention (f16 MFMA, w1 in swizzled LDS) ----------
// 1024-thread blocks (16 waves, 16 rows/wave): 64 KB w1 tile serves 16 waves,
// 2 blocks/CU -> 32 waves/CU.
__global__ __launch_bounds__(1024, 4)
void sem_w_mfma(const _Float16* __restrict__ zb,
                const _Float16* __restrict__ w1t,   // [128 n][256 k] f16
                const float* __restrict__ b1f,
                const float* __restrict__ w2f,
                float* __restrict__ wsum, int rows) {
    __shared__ _Float16 Bs[32768];      // 64 KB, 16B-chunk XOR swizzle
    __shared__ float redbuf[16][3];     // per-wave bins for block reduction
    int tid = threadIdx.x;
    {
        const f16x8* src = (const f16x8*)w1t;
#pragma unroll
        for (int it = 0; it < 4; ++it) {
            int c = it * 1024 + tid;
            int row = c >> 5, cv = c & 31;
            *(f16x8*)(Bs + ((row << 5) + (cv ^ (row & 7))) * 8) = src[c];
        }
    }
    __syncthreads();

    int wave = tid >> 6, lane = tid & 63;
    int l15 = lane & 15, quad = lane >> 4;
    int sw  = l15 & 7;
    int row0 = blockIdx.x * 256 + wave * 16;
    int lr = min(row0 + l15, rows - 1);

    f32x4 acc[8];
#pragma unroll
    for (int tn = 0; tn < 8; ++tn) acc[tn] = (f32x4){0.f, 0.f, 0.f, 0.f};

#pragma unroll
    for (int c0 = 0; c0 < 32; c0 += 4) {
        int kc = c0 * 8;
        f16x8 a = *reinterpret_cast<const f16x8*>(zb + (size_t)lr * 256 + kc + quad * 8);
#pragma unroll
        for (int tn = 0; tn < 8; ++tn) {
            int brow = tn * 16 + l15;
            f16x8 b = *reinterpret_cast<const f16x8*>(
                Bs + ((brow << 5) + ((c0 + quad) ^ sw)) * 8);
            acc[tn] = __builtin_amdgcn_mfma_f32_16x16x32_f16(a, b, acc[tn], 0, 0, 0);
        }
    }

    // epilogue: per-row tanh-dot, reduce over hidden (l15), bin by row%3
    float rowsum[4] = {0.f, 0.f, 0.f, 0.f};
#pragma unroll
    for (int tn = 0; tn < 8; ++tn) {
        int col = tn * 16 + l15;
        float b1v = b1f[col], w2v = w2f[col];
#pragma unroll
        for (int i = 0; i < 4; ++i)
            rowsum[i] += fast_tanh(acc[tn][i] + b1v) * w2v;
    }
#pragma unroll
    for (int i = 0; i < 4; ++i) {
        rowsum[i] += __shfl_xor(rowsum[i], 1);
        rowsum[i] += __shfl_xor(rowsum[i], 2);
        rowsum[i] += __shfl_xor(rowsum[i], 4);
        rowsum[i] += __shfl_xor(rowsum[i], 8);
    }
    float bins[3] = {0.f, 0.f, 0.f};
    if (l15 == 0) {
#pragma unroll
        for (int i = 0; i < 4; ++i) {
            int r = row0 + quad * 4 + i;
            if (r < rows) bins[r % 3] += rowsum[i];
        }
    }
#pragma unroll
    for (int b = 0; b < 3; ++b) {   // combine the 4 quads (lanes 0,16,32,48)
        bins[b] += __shfl_xor(bins[b], 16);
        bins[b] += __shfl_xor(bins[b], 32);
    }
    if (lane == 0) {
#pragma unroll
        for (int b = 0; b < 3; ++b) redbuf[wave][b] = bins[b];
    }
    __syncthreads();
    if (tid < 3) {                  // block-level reduce: 3 atomics per block
        float s = 0.f;
#pragma unroll
        for (int w = 0; w < 16; ++w) s += redbuf[w][tid];
        atomicAdd(&wsum[tid], s);
    }
}

// ---------- K8: combine with fused beta = softmax(mean) ----------
__global__ void combine(const _Float16* __restrict__ zb,
                        const float* __restrict__ wsum, float invN,
                        void* __restrict__ out, const int* __restrict__ flags) {
    int idx = blockIdx.x * 256 + threadIdx.x;    // over N*64
    int n = idx >> 6, c4 = (idx & 63) * 4;
    float w0 = wsum[0] * invN, w1 = wsum[1] * invN, w2 = wsum[2] * invN;
    float mx = fmaxf(w0, fmaxf(w1, w2));
    float e0 = __expf(w0 - mx), e1 = __expf(w1 - mx), e2 = __expf(w2 - mx);
    float s = 1.f / (e0 + e1 + e2);
    float b0 = e0 * s, b1 = e1 * s, b2 = e2 * s;
    const _Float16* base = zb + (size_t)n * 768 + c4;
    f16x4 z0 = *reinterpret_cast<const f16x4*>(base);
    f16x4 z1 = *reinterpret_cast<const f16x4*>(base + 256);
    f16x4 z2 = *reinterpret_cast<const f16x4*>(base + 512);
    float v[4];
#pragma unroll
    for (int i = 0; i < 4; ++i)
        v[i] = b0 * (float)z0[i] + b1 * (float)z1[i] + b2 * (float)z2[i];
    if (flags[0]) {
        ushort4 o = {f2bf(v[0]), f2bf(v[1]), f2bf(v[2]), f2bf(v[3])};
        *reinterpret_cast<ushort4*>((unsigned short*)out + (size_t)idx * 4) = o;
    } else {
        f32x4 o = {v[0], v[1], v[2], v[3]};
        *reinterpret_cast<f32x4*>((float*)out + (size_t)idx * 4) = o;
    }
}

extern "C" void kernel_launch(void* const* d_in, const int* in_sizes, int n_in,
                              void* d_out, int out_size, void* d_ws, size_t ws_size,
                              hipStream_t stream) {
    const void* h    = d_in[0];
    const void* e0   = d_in[1];
    const void* e1   = d_in[2];
    const void* e2   = d_in[3];
    const void* W    = d_in[4];
    const void* as   = d_in[5];
    const void* ad   = d_in[6];
    const void* bias = d_in[7];
    const void* w1   = d_in[8];
    const void* b1   = d_in[9];
    const void* w2   = d_in[10];

    const int N = in_sizes[0] / 256;   // 50000
    const int E = in_sizes[1] / 2;     // 400000
    const int M = 3 * N;               // 150000 segments
    const int NB = (M + 1023) >> 10;   // 147 coarse buckets

    char* ws = (char*)d_ws;
    unsigned short* xw    = (unsigned short*)(ws + XW_OFF);
    _Float16*       zb    = (_Float16*)(ws + ZB_OFF);
    unsigned short* csr   = (unsigned short*)(ws + CSR_OFF);
    int*            rs    = (int*)(ws + RS_OFF);
    unsigned short* Wt    = (unsigned short*)(ws + WT_OFF);
    _Float16*       w1t   = (_Float16*)(ws + W1T_OFF);
    float*          asf   = (float*)(ws + ASF_OFF);
    float*          adf   = (float*)(ws + ADF_OFF);
    float*          biasf = (float*)(ws + BIASF_OFF);
    float*          b1f   = (float*)(ws + B1F_OFF);
    float*          w2f   = (float*)(ws + W2F_OFF);
    float*          wsum  = (float*)(ws + WSUM_OFF);
    float*          as_   = (float*)(ws + AS_OFF);
    float*          ad_   = (float*)(ws + AD_OFF);
    int*            flags = (int*)(ws + FLAG_OFF);

    // bucket-sort scratch overlays the zb region (dead until agg_csr)
    unsigned int* bkt  = (unsigned int*)(ws + ZB_OFF);                 // NB*CAPB u32 = 9.6 MB
    int*          bcnt = (int*)(ws + ZB_OFF + (size_t)NBMAX * CAPB * 4);  // NBMAX ints

    probe<<<1, 64, 0, stream>>>((const unsigned short*)h, (const unsigned int*)e0, flags);
    ingest_params<<<907, 256, 0, stream>>>(W, as, ad, bias, w1, b1, w2,
                                           Wt, w1t, asf, adf, biasf, b1f, w2f, flags);

    // CSR build v4: two-pass LDS counting sort (replaces hist+scan+scatter)
    hipMemsetAsync(bcnt, 0, NBMAX * sizeof(int), stream);
    int aBlocks = (3 * E + CHUNKA - 1) / CHUNKA;   // 240
    bucket_a<<<aBlocks, 256, 0, stream>>>(e0, e1, e2, bcnt, bkt, E, N, NB, flags);
    bucket_b<<<NB, 256, 0, stream>>>(bcnt, bkt, rs, csr, M, NB, 3 * E);

    hipMemsetAsync(wsum, 0, 16, stream);

    int gemmBlocks = ((N + 255) / 256) * 2;        // 392
    int aggBlocks  = (N + 3) / 4;                  // 12500
    for (int p = 0; p < 3; ++p) {
        gemm_xw_mfma<<<gemmBlocks, 256, 0, stream>>>(h, Wt + p * 65536, xw,
                                                     asf + p * 256, adf + p * 256,
                                                     as_, ad_, flags, N);
        agg_csr<<<aggBlocks, 256, 0, stream>>>(csr, rs, as_, ad_, xw, biasf, zb, N, p);
    }

    int semBlocks = (M + 255) / 256;               // 586
    sem_w_mfma<<<semBlocks, 1024, 0, stream>>>(zb, w1t, b1f, w2f, wsum, M);
    combine<<<(N * 64 + 255) / 256, 256, 0, stream>>>(zb, wsum, 1.0f / (float)N, d_out, flags);
}

// Round 7
// 445.157 us; speedup vs baseline: 1.2317x; 1.0239x over previous
//
#include <hip/hip_runtime.h>
#include <hip/hip_bf16.h>

// ---------- helpers ----------
__device__ __forceinline__ float bf2f(unsigned short u) {
    union { unsigned int i; float f; } x;
    x.i = ((unsigned int)u) << 16;
    return x.f;
}
__device__ __forceinline__ unsigned short f2bf(float f) {
    union { float f; unsigned int u; } x; x.f = f;
    unsigned int r = x.u + 0x7FFFu + ((x.u >> 16) & 1u);
    return (unsigned short)(r >> 16);
}
__device__ __forceinline__ float fast_tanh(float x) {
    float a = fabsf(x);
    float t = __expf(2.f * a);
    float r = 1.f - 2.f / (t + 1.f);
    return copysignf(r, x);
}

typedef __bf16    bf16x8 __attribute__((ext_vector_type(8)));
typedef _Float16  f16x8  __attribute__((ext_vector_type(8)));
typedef _Float16  f16x4  __attribute__((ext_vector_type(4)));
typedef float     f32x4  __attribute__((ext_vector_type(4)));

// ---------- workspace byte offsets (total ~110.5 MB) ----------
#define XW_OFF     0UL            // N*256 bf16      = 25,600,000
#define ZB_OFF     25600000UL     // 3N*256 f16      = 76,800,000 (bias folded)
                                  // (bucket-sort scratch reuses this region
                                  //  before agg_csr writes zb)
#define CSR_OFF    102400000UL    // 3E u16          =  2,400,000
#define RS_OFF     107200000UL    // (3N+1) int32
#define CUR_OFF    107800064UL    // 3N int32 (unused now)
#define BS_OFF     108400128UL    // 256 int32 (unused now)
#define AS_OFF     108401152UL    // N*4 f32
#define AD_OFF     109201152UL    // N*4 f32
#define WT_OFF     110001152UL    // 3*256*256 bf16 (transposed W)
#define W1T_OFF    110394368UL    // 128*256 f16 (transposed w1)
#define ASF_OFF    110459904UL    // 768 f32
#define ADF_OFF    110462976UL
#define BIASF_OFF  110466048UL
#define B1F_OFF    110469120UL
#define W2F_OFF    110469632UL
#define WSUM_OFF   110470144UL
#define BETA_OFF   110470208UL
#define FLAG_OFF   110470272UL

// ---------- CSR-build v4 constants ----------
#define CHUNKA 5000     // edges per bucket_a block
#define NBMAX  152      // >= NB = ceil(3N/1024) = 147 ; must be <= 255 (u8)
#define CAPB   16384    // per-bucket capacity (mean 8163, +90 sigma)

// ---------- P0: dtype probe ----------
__global__ void probe(const unsigned short* __restrict__ hraw,
                      const unsigned int* __restrict__ eraw,
                      int* __restrict__ flags) {
    if (threadIdx.x == 0 && blockIdx.x == 0) {
        int sane = 0;
        for (int i = 0; i < 256; ++i) {
            unsigned int e = (hraw[i] >> 7) & 0xFF;
            if (hraw[i] != 0 && e >= 100 && e <= 150) sane++;
        }
        flags[0] = (sane >= 220) ? 1 : 0;   // 1 = bf16 inputs/outputs
        int zeros = 0;
        for (int i = 1; i < 256; i += 2) if (eraw[i] == 0u) zeros++;
        flags[1] = (zeros >= 120) ? 1 : 0;  // 1 = int64 indices
    }
}

__device__ __forceinline__ float rd_f(const void* p, int j, bool bf) {
    return bf ? bf2f(((const unsigned short*)p)[j]) : ((const float*)p)[j];
}
__device__ __forceinline__ int rd_i(const void* p, long long j, bool i64) {
    return i64 ? (int)((const long long*)p)[j] : ((const int*)p)[j];
}

// ---------- P1: canonicalize params ----------
__global__ void ingest_params(const void* W, const void* as, const void* ad, const void* bias,
                              const void* w1, const void* b1, const void* w2,
                              unsigned short* Wt, _Float16* w1t,
                              float* asf, float* adf, float* biasf,
                              float* b1f, float* w2f,
                              const int* __restrict__ flags) {
    int i = blockIdx.x * 256 + threadIdx.x;
    bool bf = flags[0] != 0;
    if (i < 196608) {                              // Wt[p][n][k] = W[p][k][n]
        int p = i >> 16, n = (i >> 8) & 255, k = i & 255;
        Wt[i] = f2bf(rd_f(W, p * 65536 + k * 256 + n, bf));
    } else if (i < 229376) {                       // w1t[n][k] = w1[k][n], fp16
        int j = i - 196608;
        int n = j >> 8, k = j & 255;
        w1t[j] = (_Float16)rd_f(w1, k * 128 + n, bf);
    } else if (i < 230144) {
        int j = i - 229376; asf[j] = rd_f(as, j, bf);
    } else if (i < 230912) {
        int j = i - 230144; adf[j] = rd_f(ad, j, bf);
    } else if (i < 231680) {
        int j = i - 230912; biasf[j] = rd_f(bias, j, bf);
    } else if (i < 231808) {
        int j = i - 231680; b1f[j] = rd_f(b1, j, bf);
    } else if (i < 231936) {
        int j = i - 231808; w2f[j] = rd_f(w2, j, bf);
    }
}

// ---------- CSR build v4: LDS-staged two-pass counting sort ----------
// bucket = seg >> 10 (1024 segments/bucket, NB = 147 buckets).
// bucket_a: each block sorts its 5000-edge chunk by bucket in LDS, reserves
// per-(block,bucket) ranges with ONE global atomic each, writes runs coalesced.
__global__ __launch_bounds__(256)
void bucket_a(const void* e0, const void* e1, const void* e2,
              int* __restrict__ bcnt, unsigned int* __restrict__ bkt,
              int E, int N, int NB, const int* __restrict__ flags) {
    __shared__ unsigned int  ent[CHUNKA];
    __shared__ unsigned char bck[CHUNKA];
    __shared__ unsigned int  sent[CHUNKA];
    __shared__ unsigned char sbck[CHUNKA];
    __shared__ int lcnt[NBMAX], lpre[NBMAX], lbase[NBMAX], lcur[NBMAX];
    int tid = threadIdx.x;
    int s = blockIdx.x * CHUNKA;
    int tot = 3 * E;
    int n = min(tot, s + CHUNKA) - s;
    for (int b = tid; b < NBMAX; b += 256) { lcnt[b] = 0; lcur[b] = 0; }
    __syncthreads();
    bool i64 = flags[1] != 0;
    for (int i = tid; i < n; i += 256) {
        int idx = s + i;
        int p = (idx >= 2 * E) ? 2 : (idx >= E) ? 1 : 0;
        int j = idx - p * E;
        const void* ep = (p == 0) ? e0 : (p == 1) ? e1 : e2;
        unsigned int src = (unsigned int)rd_i(ep, j, i64);
        unsigned int dst = (unsigned int)rd_i(ep, (long long)E + j, i64);
        int seg = p * N + (int)dst;
        int b = seg >> 10;
        ent[i] = src | ((unsigned int)(seg & 1023) << 16);
        bck[i] = (unsigned char)b;
        atomicAdd(&lcnt[b], 1);
    }
    __syncthreads();
    if (tid == 0) {                       // block-local exclusive prefix (147 iters)
        int run = 0;
        for (int b = 0; b < NB; ++b) { lpre[b] = run; run += lcnt[b]; }
    }
    if (tid < NB) lbase[tid] = atomicAdd(&bcnt[tid], lcnt[tid]);   // global reserve
    __syncthreads();
    for (int i = tid; i < n; i += 256) {  // LDS counting-sort placement
        int b = bck[i];
        int pos = lpre[b] + atomicAdd(&lcur[b], 1);
        sent[pos] = ent[i];
        sbck[pos] = (unsigned char)b;
    }
    __syncthreads();
    for (int q = tid; q < n; q += 256) {  // coalesced run write-out
        int b = sbck[q];
        int gpos = lbase[b] + (q - lpre[b]);
        if (gpos < CAPB) bkt[(size_t)b * CAPB + gpos] = sent[q];
    }
}

// bucket_b: per bucket, LDS per-seg histogram + prefix -> writes rs directly
// and places edges into its contiguous csr region (full-line writebacks).
__global__ __launch_bounds__(256)
void bucket_b(const int* __restrict__ bcnt, const unsigned int* __restrict__ bkt,
              int* __restrict__ rs, unsigned short* __restrict__ csr,
              int M, int NB, int tot) {
    __shared__ int scnt[1024];
    __shared__ int spre[1024];
    __shared__ int part[256];
    int b = blockIdx.x, tid = threadIdx.x;
    // base = prefix sum of bcnt[0..b)
    int acc = 0;
    for (int i = tid; i < b; i += 256) acc += min(bcnt[i], CAPB);
    part[tid] = acc; __syncthreads();
    for (int o = 128; o > 0; o >>= 1) {
        if (tid < o) part[tid] += part[tid + o];
        __syncthreads();
    }
    int base = part[0];
    int cnt = min(bcnt[b], CAPB);
    for (int i = tid; i < 1024; i += 256) scnt[i] = 0;
    __syncthreads();
    const unsigned int* src = bkt + (size_t)b * CAPB;
    for (int i = tid; i < cnt; i += 256)
        atomicAdd(&scnt[src[i] >> 16], 1);
    __syncthreads();
    // exclusive prefix over 1024 counters (4 items/thread + block scan)
    int a0 = scnt[tid * 4], a1 = scnt[tid * 4 + 1], a2 = scnt[tid * 4 + 2], a3 = scnt[tid * 4 + 3];
    int psum = a0 + a1 + a2 + a3;
    part[tid] = psum; __syncthreads();
    for (int o = 1; o < 256; o <<= 1) {
        int tmp = (tid >= o) ? part[tid - o] : 0;
        __syncthreads();
        part[tid] += tmp;
        __syncthreads();
    }
    int pb = part[tid] - psum;
    spre[tid * 4]     = pb;
    spre[tid * 4 + 1] = pb + a0;
    spre[tid * 4 + 2] = pb + a0 + a1;
    spre[tid * 4 + 3] = pb + a0 + a1 + a2;
    __syncthreads();
    // write rs for this bucket's segments; reset cursors
    for (int i = tid; i < 1024; i += 256) {
        int seg = b * 1024 + i;
        if (seg < M) rs[seg] = base + spre[i];
        scnt[i] = 0;
    }
    if (b == NB - 1 && tid == 0) rs[M] = tot;
    __syncthreads();
    // place (random within single-owner 16KB region -> full-line writebacks)
    for (int i = tid; i < cnt; i += 256) {
        unsigned int u = src[i];
        int slow = u >> 16;
        int pos = spre[slow] + atomicAdd(&scnt[slow], 1);
        csr[base + pos] = (unsigned short)(u & 0xFFFFu);
    }
}

// ---------- K1: xw = h @ W[p] (MFMA, B in swizzled LDS) ----------
// v2: 1024-thread blocks (16 waves, 16 rows/wave): 64 KB B tile serves 16
// waves; grid 392 blocks -> 6272 waves (24.5/CU) instead of 1568 (6/CU).
__global__ __launch_bounds__(1024, 4)
void gemm_xw_mfma(const void* __restrict__ h,
                  const unsigned short* __restrict__ Wtp,   // [256 n][256 k] bf16
                  unsigned short* __restrict__ xw,
                  const float* __restrict__ asf,            // [256] this path
                  const float* __restrict__ adf,
                  float* __restrict__ as_, float* __restrict__ ad_,
                  const int* __restrict__ flags, int N) {
    __shared__ __bf16 Bs[32768];        // 64 KB: 128 rows x 256 k, 16B-chunk XOR swizzle
    int tid  = threadIdx.x;
    int ch   = blockIdx.x & 1;          // col half
    int rg   = blockIdx.x >> 1;         // row group (256 rows)
    // stage B half into LDS (chunk c of row r -> slot c ^ (r&7))
    {
        const bf16x8* src = (const bf16x8*)Wtp;
#pragma unroll
        for (int it = 0; it < 4; ++it) {
            int c = it * 1024 + tid;
            int row = c >> 5, cv = c & 31;
            *(bf16x8*)(Bs + ((row << 5) + (cv ^ (row & 7))) * 8) =
                src[(ch * 128 + row) * 32 + cv];
        }
    }
    __syncthreads();

    int wave = tid >> 6, lane = tid & 63;
    int l15 = lane & 15, quad = lane >> 4;
    int sw  = l15 & 7;
    int row0 = rg * 256 + wave * 16;
    bool bfm = flags[0] != 0;

    int lr = min(row0 + l15, N - 1);

    f32x4 acc[8];
#pragma unroll
    for (int tn = 0; tn < 8; ++tn) acc[tn] = (f32x4){0.f, 0.f, 0.f, 0.f};

#pragma unroll
    for (int c0 = 0; c0 < 32; c0 += 4) {          // k chunk base (16B units), k = c0*8
        int kc = c0 * 8;
        bf16x8 a;
        {
            size_t off = (size_t)lr * 256 + kc + quad * 8;
            if (bfm) {
                a = *reinterpret_cast<const bf16x8*>((const __bf16*)h + off);
            } else {
                f32x4 u0 = *reinterpret_cast<const f32x4*>((const float*)h + off);
                f32x4 u1 = *reinterpret_cast<const f32x4*>((const float*)h + off + 4);
#pragma unroll
                for (int j = 0; j < 4; ++j) { a[j] = (__bf16)u0[j]; a[4 + j] = (__bf16)u1[j]; }
            }
        }
#pragma unroll
        for (int tn = 0; tn < 8; ++tn) {
            int row = tn * 16 + l15;
            bf16x8 b = *reinterpret_cast<const bf16x8*>(
                Bs + ((row << 5) + ((c0 + quad) ^ sw)) * 8);
            acc[tn] = __builtin_amdgcn_mfma_f32_16x16x32_bf16(a, b, acc[tn], 0, 0, 0);
        }
    }

    // epilogue: store xw + fused alpha (wave owns heads {2ch, 2ch+1})
    int rbase = row0 + quad * 4;
#pragma unroll
    for (int tn = 0; tn < 8; ++tn) {
        int c = ch * 128 + tn * 16 + l15;
#pragma unroll
        for (int i = 0; i < 4; ++i) {
            int r = rbase + i;
            if (r < N) xw[(size_t)r * 256 + c] = f2bf(acc[tn][i]);
        }
    }
    float ss[2][4] = {{0.f,0.f,0.f,0.f},{0.f,0.f,0.f,0.f}};
    float dd[2][4] = {{0.f,0.f,0.f,0.f},{0.f,0.f,0.f,0.f}};
#pragma unroll
    for (int tn = 0; tn < 8; ++tn) {
        int c = ch * 128 + tn * 16 + l15;
        float sv = asf[c], dv = adf[c];
        int hs = tn >> 2;
#pragma unroll
        for (int i = 0; i < 4; ++i) {
            ss[hs][i] += acc[tn][i] * sv;
            dd[hs][i] += acc[tn][i] * dv;
        }
    }
#pragma unroll
    for (int hs = 0; hs < 2; ++hs)
#pragma unroll
        for (int i = 0; i < 4; ++i) {
            float s = ss[hs][i], d = dd[hs][i];
            s += __shfl_xor(s, 1); d += __shfl_xor(d, 1);
            s += __shfl_xor(s, 2); d += __shfl_xor(d, 2);
            s += __shfl_xor(s, 4); d += __shfl_xor(d, 4);
            s += __shfl_xor(s, 8); d += __shfl_xor(d, 8);
            ss[hs][i] = s; dd[hs][i] = d;
        }
    if (l15 == 0) {
#pragma unroll
        for (int hs = 0; hs < 2; ++hs)
#pragma unroll
            for (int i = 0; i < 4; ++i) {
                int r = rbase + i;
                if (r < N) {
                    int g = r * 4 + ch * 2 + hs;
                    as_[g] = ss[hs][i];
                    ad_[g] = dd[hs][i];
                }
            }
    }
}

__device__ __forceinline__ float leaky(float v) { return v > 0.f ? v : 0.2f * v; }

// ---------- K5: CSR online-softmax aggregate -> z' fp16 (bias folded) ----------
// u16 csr; one-iteration software-pipeline lookahead on score + row loads.
__global__ void agg_csr(const unsigned short* __restrict__ csr, const int* __restrict__ rs,
                        const float* __restrict__ as_, const float* __restrict__ ad_,
                        const unsigned short* __restrict__ xw,
                        const float* __restrict__ biasf,
                        _Float16* __restrict__ zb, int N, int p) {
    int d = blockIdx.x * 4 + (threadIdx.x >> 6);
    if (d >= N) return;
    int lane = threadIdx.x & 63;
    int h = lane >> 4;
    int seg = p * N + d;
    int start = rs[seg], end = rs[seg + 1];

    float adh = ad_[d * 4 + h];
    float m = leaky(as_[d * 4 + h] + adh);
    float l = 1.f;
    float a0, a1, a2, a3;
    {
        ushort4 u = *reinterpret_cast<const ushort4*>(xw + (size_t)d * 256 + lane * 4);
        a0 = bf2f(u.x); a1 = bf2f(u.y); a2 = bf2f(u.z); a3 = bf2f(u.w);
    }
    if (start < end) {
        int srcA = csr[start];
        float sA = as_[srcA * 4 + h];
        ushort4 uA = *reinterpret_cast<const ushort4*>(xw + (size_t)srcA * 256 + lane * 4);
        for (int j = start; j < end; ++j) {
            // issue next-neighbor loads before this iteration's math
            int srcB = (j + 1 < end) ? csr[j + 1] : 0;
            float sB = as_[srcB * 4 + h];
            ushort4 uB = *reinterpret_cast<const ushort4*>(xw + (size_t)srcB * 256 + lane * 4);
            float v = leaky(sA + adh);
            float mn = fmaxf(m, v);
            float c = __expf(m - mn);
            float w = __expf(v - mn);
            m = mn;
            l = l * c + w;
            a0 = a0 * c + w * bf2f(uA.x);
            a1 = a1 * c + w * bf2f(uA.y);
            a2 = a2 * c + w * bf2f(uA.z);
            a3 = a3 * c + w * bf2f(uA.w);
            sA = sB; uA = uB;
        }
    }
    float inv = 1.f / l;
    int col = lane * 4;
    const float* bp = biasf + p * 256 + col;
    f16x4 o = {(_Float16)(a0 * inv + bp[0]), (_Float16)(a1 * inv + bp[1]),
               (_Float16)(a2 * inv + bp[2]), (_Float16)(a3 * inv + bp[3])};
    *reinterpret_cast<f16x4*>(zb + ((size_t)d * 3 + p) * 256 + col) = o;
}

// ---------- K6: semantic attention (f16 MFMA, w1 in swizzled LDS) ----------
// 1024-thread blocks (16 waves, 16 rows/wave): 64 KB w1 tile serves 16 waves,
// 2 blocks/CU -> 32 waves/CU.
__global__ __launch_bounds__(1024, 4)
void sem_w_mfma(const _Float16* __restrict__ zb,
                const _Float16* __restrict__ w1t,   // [128 n][256 k] f16
                const float* __restrict__ b1f,
                const float* __restrict__ w2f,
                float* __restrict__ wsum, int rows) {
    __shared__ _Float16 Bs[32768];      // 64 KB, 16B-chunk XOR swizzle
    __shared__ float redbuf[16][3];     // per-wave bins for block reduction
    int tid = threadIdx.x;
    {
        const f16x8* src = (const f16x8*)w1t;
#pragma unroll
        for (int it = 0; it < 4; ++it) {
            int c = it * 1024 + tid;
            int row = c >> 5, cv = c & 31;
            *(f16x8*)(Bs + ((row << 5) + (cv ^ (row & 7))) * 8) = src[c];
        }
    }
    __syncthreads();

    int wave = tid >> 6, lane = tid & 63;
    int l15 = lane & 15, quad = lane >> 4;
    int sw  = l15 & 7;
    int row0 = blockIdx.x * 256 + wave * 16;
    int lr = min(row0 + l15, rows - 1);

    f32x4 acc[8];
#pragma unroll
    for (int tn = 0; tn < 8; ++tn) acc[tn] = (f32x4){0.f, 0.f, 0.f, 0.f};

#pragma unroll
    for (int c0 = 0; c0 < 32; c0 += 4) {
        int kc = c0 * 8;
        f16x8 a = *reinterpret_cast<const f16x8*>(zb + (size_t)lr * 256 + kc + quad * 8);
#pragma unroll
        for (int tn = 0; tn < 8; ++tn) {
            int brow = tn * 16 + l15;
            f16x8 b = *reinterpret_cast<const f16x8*>(
                Bs + ((brow << 5) + ((c0 + quad) ^ sw)) * 8);
            acc[tn] = __builtin_amdgcn_mfma_f32_16x16x32_f16(a, b, acc[tn], 0, 0, 0);
        }
    }

    // epilogue: per-row tanh-dot, reduce over hidden (l15), bin by row%3
    float rowsum[4] = {0.f, 0.f, 0.f, 0.f};
#pragma unroll
    for (int tn = 0; tn < 8; ++tn) {
        int col = tn * 16 + l15;
        float b1v = b1f[col], w2v = w2f[col];
#pragma unroll
        for (int i = 0; i < 4; ++i)
            rowsum[i] += fast_tanh(acc[tn][i] + b1v) * w2v;
    }
#pragma unroll
    for (int i = 0; i < 4; ++i) {
        rowsum[i] += __shfl_xor(rowsum[i], 1);
        rowsum[i] += __shfl_xor(rowsum[i], 2);
        rowsum[i] += __shfl_xor(rowsum[i], 4);
        rowsum[i] += __shfl_xor(rowsum[i], 8);
    }
    float bins[3] = {0.f, 0.f, 0.f};
    if (l15 == 0) {
#pragma unroll
        for (int i = 0; i < 4; ++i) {
            int r = row0 + quad * 4 + i;
            if (r < rows) bins[r % 3] += rowsum[i];
        }
    }
#pragma unroll
    for (int b = 0; b < 3; ++b) {   // combine the 4 quads (lanes 0,16,32,48)
        bins[b] += __shfl_xor(bins[b], 16);
        bins[b] += __shfl_xor(bins[b], 32);
    }
    if (lane == 0) {
#pragma unroll
        for (int b = 0; b < 3; ++b) redbuf[wave][b] = bins[b];
    }
    __syncthreads();
    if (tid < 3) {                  // block-level reduce: 3 atomics per block
        float s = 0.f;
#pragma unroll
        for (int w = 0; w < 16; ++w) s += redbuf[w][tid];
        atomicAdd(&wsum[tid], s);
    }
}

// ---------- K8: combine with fused beta = softmax(mean) ----------
__global__ void combine(const _Float16* __restrict__ zb,
                        const float* __restrict__ wsum, float invN,
                        void* __restrict__ out, const int* __restrict__ flags) {
    int idx = blockIdx.x * 256 + threadIdx.x;    // over N*64
    int n = idx >> 6, c4 = (idx & 63) * 4;
    float w0 = wsum[0] * invN, w1 = wsum[1] * invN, w2 = wsum[2] * invN;
    float mx = fmaxf(w0, fmaxf(w1, w2));
    float e0 = __expf(w0 - mx), e1 = __expf(w1 - mx), e2 = __expf(w2 - mx);
    float s = 1.f / (e0 + e1 + e2);
    float b0 = e0 * s, b1 = e1 * s, b2 = e2 * s;
    const _Float16* base = zb + (size_t)n * 768 + c4;
    f16x4 z0 = *reinterpret_cast<const f16x4*>(base);
    f16x4 z1 = *reinterpret_cast<const f16x4*>(base + 256);
    f16x4 z2 = *reinterpret_cast<const f16x4*>(base + 512);
    float v[4];
#pragma unroll
    for (int i = 0; i < 4; ++i)
        v[i] = b0 * (float)z0[i] + b1 * (float)z1[i] + b2 * (float)z2[i];
    if (flags[0]) {
        ushort4 o = {f2bf(v[0]), f2bf(v[1]), f2bf(v[2]), f2bf(v[3])};
        *reinterpret_cast<ushort4*>((unsigned short*)out + (size_t)idx * 4) = o;
    } else {
        f32x4 o = {v[0], v[1], v[2], v[3]};
        *reinterpret_cast<f32x4*>((float*)out + (size_t)idx * 4) = o;
    }
}

extern "C" void kernel_launch(void* const* d_in, const int* in_sizes, int n_in,
                              void* d_out, int out_size, void* d_ws, size_t ws_size,
                              hipStream_t stream) {
    const void* h    = d_in[0];
    const void* e0   = d_in[1];
    const void* e1   = d_in[2];
    const void* e2   = d_in[3];
    const void* W    = d_in[4];
    const void* as   = d_in[5];
    const void* ad   = d_in[6];
    const void* bias = d_in[7];
    const void* w1   = d_in[8];
    const void* b1   = d_in[9];
    const void* w2   = d_in[10];

    const int N = in_sizes[0] / 256;   // 50000
    const int E = in_sizes[1] / 2;     // 400000
    const int M = 3 * N;               // 150000 segments
    const int NB = (M + 1023) >> 10;   // 147 coarse buckets

    char* ws = (char*)d_ws;
    unsigned short* xw    = (unsigned short*)(ws + XW_OFF);
    _Float16*       zb    = (_Float16*)(ws + ZB_OFF);
    unsigned short* csr   = (unsigned short*)(ws + CSR_OFF);
    int*            rs    = (int*)(ws + RS_OFF);
    unsigned short* Wt    = (unsigned short*)(ws + WT_OFF);
    _Float16*       w1t   = (_Float16*)(ws + W1T_OFF);
    float*          asf   = (float*)(ws + ASF_OFF);
    float*          adf   = (float*)(ws + ADF_OFF);
    float*          biasf = (float*)(ws + BIASF_OFF);
    float*          b1f   = (float*)(ws + B1F_OFF);
    float*          w2f   = (float*)(ws + W2F_OFF);
    float*          wsum  = (float*)(ws + WSUM_OFF);
    float*          as_   = (float*)(ws + AS_OFF);
    float*          ad_   = (float*)(ws + AD_OFF);
    int*            flags = (int*)(ws + FLAG_OFF);

    // bucket-sort scratch overlays the zb region (dead until agg_csr)
    unsigned int* bkt  = (unsigned int*)(ws + ZB_OFF);                 // NB*CAPB u32 = 9.6 MB
    int*          bcnt = (int*)(ws + ZB_OFF + (size_t)NBMAX * CAPB * 4);  // NBMAX ints

    probe<<<1, 64, 0, stream>>>((const unsigned short*)h, (const unsigned int*)e0, flags);
    ingest_params<<<907, 256, 0, stream>>>(W, as, ad, bias, w1, b1, w2,
                                           Wt, w1t, asf, adf, biasf, b1f, w2f, flags);

    // CSR build v4: two-pass LDS counting sort (replaces hist+scan+scatter)
    hipMemsetAsync(bcnt, 0, NBMAX * sizeof(int), stream);
    int aBlocks = (3 * E + CHUNKA - 1) / CHUNKA;   // 240
    bucket_a<<<aBlocks, 256, 0, stream>>>(e0, e1, e2, bcnt, bkt, E, N, NB, flags);
    bucket_b<<<NB, 256, 0, stream>>>(bcnt, bkt, rs, csr, M, NB, 3 * E);

    hipMemsetAsync(wsum, 0, 16, stream);

    int gemmBlocks = ((N + 255) / 256) * 2;        // 392
    int aggBlocks  = (N + 3) / 4;                  // 12500
    for (int p = 0; p < 3; ++p) {
        gemm_xw_mfma<<<gemmBlocks, 1024, 0, stream>>>(h, Wt + p * 65536, xw,
                                                      asf + p * 256, adf + p * 256,
                                                      as_, ad_, flags, N);
        agg_csr<<<aggBlocks, 256, 0, stream>>>(csr, rs, as_, ad_, xw, biasf, zb, N, p);
    }

    int semBlocks = (M + 255) / 256;               // 586
    sem_w_mfma<<<semBlocks, 1024, 0, stream>>>(zb, w1t, b1f, w2f, wsum, M);
    combine<<<(N * 64 + 255) / 256, 256, 0, stream>>>(zb, wsum, 1.0f / (float)N, d_out, flags);
}

// Round 8
// 443.406 us; speedup vs baseline: 1.2365x; 1.0040x over previous
//
#include <hip/hip_runtime.h>
#include <hip/hip_bf16.h>

// ---------- helpers ----------
__device__ __forceinline__ float bf2f(unsigned short u) {
    union { unsigned int i; float f; } x;
    x.i = ((unsigned int)u) << 16;
    return x.f;
}
__device__ __forceinline__ unsigned short f2bf(float f) {
    union { float f; unsigned int u; } x; x.f = f;
    unsigned int r = x.u + 0x7FFFu + ((x.u >> 16) & 1u);
    return (unsigned short)(r >> 16);
}
__device__ __forceinline__ float fast_tanh(float x) {
    float a = fabsf(x);
    float t = __expf(2.f * a);
    float r = 1.f - 2.f / (t + 1.f);
    return copysignf(r, x);
}

typedef __bf16    bf16x8 __attribute__((ext_vector_type(8)));
typedef _Float16  f16x8  __attribute__((ext_vector_type(8)));
typedef _Float16  f16x4  __attribute__((ext_vector_type(4)));
typedef float     f32x4  __attribute__((ext_vector_type(4)));
typedef unsigned short u16x8 __attribute__((ext_vector_type(8)));

// ---------- workspace byte offsets (total ~110.5 MB) ----------
#define XW_OFF     0UL            // N*256 bf16      = 25,600,000
#define ZB_OFF     25600000UL     // 3N*256 f16      = 76,800,000 (bias folded)
                                  // (bucket-sort scratch reuses this region
                                  //  before agg_csr writes zb)
#define CSR_OFF    102400000UL    // 3E u16          =  2,400,000
#define RS_OFF     107200000UL    // (3N+1) int32
#define CUR_OFF    107800064UL    // 3N int32 (unused now)
#define BS_OFF     108400128UL    // 256 int32 (unused now)
#define AS_OFF     108401152UL    // N*4 f32
#define AD_OFF     109201152UL    // N*4 f32
#define WT_OFF     110001152UL    // 3*256*256 bf16 (transposed W)
#define W1T_OFF    110394368UL    // 128*256 f16 (transposed w1)
#define ASF_OFF    110459904UL    // 768 f32
#define ADF_OFF    110462976UL
#define BIASF_OFF  110466048UL
#define B1F_OFF    110469120UL
#define W2F_OFF    110469632UL
#define WSUM_OFF   110470144UL
#define BETA_OFF   110470208UL
#define FLAG_OFF   110470272UL

// ---------- CSR-build v4 constants ----------
#define CHUNKA 5000     // edges per bucket_a block
#define NBMAX  152      // >= NB = ceil(3N/1024) = 147 ; must be <= 255 (u8)
#define CAPB   16384    // per-bucket capacity (mean 8163, +90 sigma)

// ---------- P0: dtype probe ----------
__global__ void probe(const unsigned short* __restrict__ hraw,
                      const unsigned int* __restrict__ eraw,
                      int* __restrict__ flags) {
    if (threadIdx.x == 0 && blockIdx.x == 0) {
        int sane = 0;
        for (int i = 0; i < 256; ++i) {
            unsigned int e = (hraw[i] >> 7) & 0xFF;
            if (hraw[i] != 0 && e >= 100 && e <= 150) sane++;
        }
        flags[0] = (sane >= 220) ? 1 : 0;   // 1 = bf16 inputs/outputs
        int zeros = 0;
        for (int i = 1; i < 256; i += 2) if (eraw[i] == 0u) zeros++;
        flags[1] = (zeros >= 120) ? 1 : 0;  // 1 = int64 indices
    }
}

__device__ __forceinline__ float rd_f(const void* p, int j, bool bf) {
    return bf ? bf2f(((const unsigned short*)p)[j]) : ((const float*)p)[j];
}
__device__ __forceinline__ int rd_i(const void* p, long long j, bool i64) {
    return i64 ? (int)((const long long*)p)[j] : ((const int*)p)[j];
}

// ---------- P1: canonicalize params ----------
__global__ void ingest_params(const void* W, const void* as, const void* ad, const void* bias,
                              const void* w1, const void* b1, const void* w2,
                              unsigned short* Wt, _Float16* w1t,
                              float* asf, float* adf, float* biasf,
                              float* b1f, float* w2f,
                              const int* __restrict__ flags) {
    int i = blockIdx.x * 256 + threadIdx.x;
    bool bf = flags[0] != 0;
    if (i < 196608) {                              // Wt[p][n][k] = W[p][k][n]
        int p = i >> 16, n = (i >> 8) & 255, k = i & 255;
        Wt[i] = f2bf(rd_f(W, p * 65536 + k * 256 + n, bf));
    } else if (i < 229376) {                       // w1t[n][k] = w1[k][n], fp16
        int j = i - 196608;
        int n = j >> 8, k = j & 255;
        w1t[j] = (_Float16)rd_f(w1, k * 128 + n, bf);
    } else if (i < 230144) {
        int j = i - 229376; asf[j] = rd_f(as, j, bf);
    } else if (i < 230912) {
        int j = i - 230144; adf[j] = rd_f(ad, j, bf);
    } else if (i < 231680) {
        int j = i - 230912; biasf[j] = rd_f(bias, j, bf);
    } else if (i < 231808) {
        int j = i - 231680; b1f[j] = rd_f(b1, j, bf);
    } else if (i < 231936) {
        int j = i - 231808; w2f[j] = rd_f(w2, j, bf);
    }
}

// ---------- CSR build v4: LDS-staged two-pass counting sort ----------
// bucket = seg >> 10 (1024 segments/bucket, NB = 147 buckets).
// bucket_a: each block sorts its 5000-edge chunk by bucket in LDS, reserves
// per-(block,bucket) ranges with ONE global atomic each, writes runs coalesced.
__global__ __launch_bounds__(256)
void bucket_a(const void* e0, const void* e1, const void* e2,
              int* __restrict__ bcnt, unsigned int* __restrict__ bkt,
              int E, int N, int NB, const int* __restrict__ flags) {
    __shared__ unsigned int  ent[CHUNKA];
    __shared__ unsigned char bck[CHUNKA];
    __shared__ unsigned int  sent[CHUNKA];
    __shared__ unsigned char sbck[CHUNKA];
    __shared__ int lcnt[NBMAX], lpre[NBMAX], lbase[NBMAX], lcur[NBMAX];
    int tid = threadIdx.x;
    int s = blockIdx.x * CHUNKA;
    int tot = 3 * E;
    int n = min(tot, s + CHUNKA) - s;
    for (int b = tid; b < NBMAX; b += 256) { lcnt[b] = 0; lcur[b] = 0; }
    __syncthreads();
    bool i64 = flags[1] != 0;
    for (int i = tid; i < n; i += 256) {
        int idx = s + i;
        int p = (idx >= 2 * E) ? 2 : (idx >= E) ? 1 : 0;
        int j = idx - p * E;
        const void* ep = (p == 0) ? e0 : (p == 1) ? e1 : e2;
        unsigned int src = (unsigned int)rd_i(ep, j, i64);
        unsigned int dst = (unsigned int)rd_i(ep, (long long)E + j, i64);
        int seg = p * N + (int)dst;
        int b = seg >> 10;
        ent[i] = src | ((unsigned int)(seg & 1023) << 16);
        bck[i] = (unsigned char)b;
        atomicAdd(&lcnt[b], 1);
    }
    __syncthreads();
    if (tid == 0) {                       // block-local exclusive prefix (147 iters)
        int run = 0;
        for (int b = 0; b < NB; ++b) { lpre[b] = run; run += lcnt[b]; }
    }
    if (tid < NB) lbase[tid] = atomicAdd(&bcnt[tid], lcnt[tid]);   // global reserve
    __syncthreads();
    for (int i = tid; i < n; i += 256) {  // LDS counting-sort placement
        int b = bck[i];
        int pos = lpre[b] + atomicAdd(&lcur[b], 1);
        sent[pos] = ent[i];
        sbck[pos] = (unsigned char)b;
    }
    __syncthreads();
    for (int q = tid; q < n; q += 256) {  // coalesced run write-out
        int b = sbck[q];
        int gpos = lbase[b] + (q - lpre[b]);
        if (gpos < CAPB) bkt[(size_t)b * CAPB + gpos] = sent[q];
    }
}

// bucket_b: per bucket, LDS per-seg histogram + prefix -> writes rs directly
// and places edges into its contiguous csr region (full-line writebacks).
__global__ __launch_bounds__(256)
void bucket_b(const int* __restrict__ bcnt, const unsigned int* __restrict__ bkt,
              int* __restrict__ rs, unsigned short* __restrict__ csr,
              int M, int NB, int tot) {
    __shared__ int scnt[1024];
    __shared__ int spre[1024];
    __shared__ int part[256];
    int b = blockIdx.x, tid = threadIdx.x;
    // base = prefix sum of bcnt[0..b)
    int acc = 0;
    for (int i = tid; i < b; i += 256) acc += min(bcnt[i], CAPB);
    part[tid] = acc; __syncthreads();
    for (int o = 128; o > 0; o >>= 1) {
        if (tid < o) part[tid] += part[tid + o];
        __syncthreads();
    }
    int base = part[0];
    int cnt = min(bcnt[b], CAPB);
    for (int i = tid; i < 1024; i += 256) scnt[i] = 0;
    __syncthreads();
    const unsigned int* src = bkt + (size_t)b * CAPB;
    for (int i = tid; i < cnt; i += 256)
        atomicAdd(&scnt[src[i] >> 16], 1);
    __syncthreads();
    // exclusive prefix over 1024 counters (4 items/thread + block scan)
    int a0 = scnt[tid * 4], a1 = scnt[tid * 4 + 1], a2 = scnt[tid * 4 + 2], a3 = scnt[tid * 4 + 3];
    int psum = a0 + a1 + a2 + a3;
    part[tid] = psum; __syncthreads();
    for (int o = 1; o < 256; o <<= 1) {
        int tmp = (tid >= o) ? part[tid - o] : 0;
        __syncthreads();
        part[tid] += tmp;
        __syncthreads();
    }
    int pb = part[tid] - psum;
    spre[tid * 4]     = pb;
    spre[tid * 4 + 1] = pb + a0;
    spre[tid * 4 + 2] = pb + a0 + a1;
    spre[tid * 4 + 3] = pb + a0 + a1 + a2;
    __syncthreads();
    // write rs for this bucket's segments; reset cursors
    for (int i = tid; i < 1024; i += 256) {
        int seg = b * 1024 + i;
        if (seg < M) rs[seg] = base + spre[i];
        scnt[i] = 0;
    }
    if (b == NB - 1 && tid == 0) rs[M] = tot;
    __syncthreads();
    // place (random within single-owner 16KB region -> full-line writebacks)
    for (int i = tid; i < cnt; i += 256) {
        unsigned int u = src[i];
        int slow = u >> 16;
        int pos = spre[slow] + atomicAdd(&scnt[slow], 1);
        csr[base + pos] = (unsigned short)(u & 0xFFFFu);
    }
}

// ---------- K1: xw = h @ W[p] (MFMA, B in swizzled LDS) ----------
// 1024-thread blocks (16 waves, 16 rows/wave): 64 KB B tile serves 16
// waves; grid 392 blocks -> 6272 waves (24.5/CU).
__global__ __launch_bounds__(1024, 4)
void gemm_xw_mfma(const void* __restrict__ h,
                  const unsigned short* __restrict__ Wtp,   // [256 n][256 k] bf16
                  unsigned short* __restrict__ xw,
                  const float* __restrict__ asf,            // [256] this path
                  const float* __restrict__ adf,
                  float* __restrict__ as_, float* __restrict__ ad_,
                  const int* __restrict__ flags, int N) {
    __shared__ __bf16 Bs[32768];        // 64 KB: 128 rows x 256 k, 16B-chunk XOR swizzle
    int tid  = threadIdx.x;
    int ch   = blockIdx.x & 1;          // col half
    int rg   = blockIdx.x >> 1;         // row group (256 rows)
    // stage B half into LDS (chunk c of row r -> slot c ^ (r&7))
    {
        const bf16x8* src = (const bf16x8*)Wtp;
#pragma unroll
        for (int it = 0; it < 4; ++it) {
            int c = it * 1024 + tid;
            int row = c >> 5, cv = c & 31;
            *(bf16x8*)(Bs + ((row << 5) + (cv ^ (row & 7))) * 8) =
                src[(ch * 128 + row) * 32 + cv];
        }
    }
    __syncthreads();

    int wave = tid >> 6, lane = tid & 63;
    int l15 = lane & 15, quad = lane >> 4;
    int sw  = l15 & 7;
    int row0 = rg * 256 + wave * 16;
    bool bfm = flags[0] != 0;

    int lr = min(row0 + l15, N - 1);

    f32x4 acc[8];
#pragma unroll
    for (int tn = 0; tn < 8; ++tn) acc[tn] = (f32x4){0.f, 0.f, 0.f, 0.f};

#pragma unroll
    for (int c0 = 0; c0 < 32; c0 += 4) {          // k chunk base (16B units), k = c0*8
        int kc = c0 * 8;
        bf16x8 a;
        {
            size_t off = (size_t)lr * 256 + kc + quad * 8;
            if (bfm) {
                a = *reinterpret_cast<const bf16x8*>((const __bf16*)h + off);
            } else {
                f32x4 u0 = *reinterpret_cast<const f32x4*>((const float*)h + off);
                f32x4 u1 = *reinterpret_cast<const f32x4*>((const float*)h + off + 4);
#pragma unroll
                for (int j = 0; j < 4; ++j) { a[j] = (__bf16)u0[j]; a[4 + j] = (__bf16)u1[j]; }
            }
        }
#pragma unroll
        for (int tn = 0; tn < 8; ++tn) {
            int row = tn * 16 + l15;
            bf16x8 b = *reinterpret_cast<const bf16x8*>(
                Bs + ((row << 5) + ((c0 + quad) ^ sw)) * 8);
            acc[tn] = __builtin_amdgcn_mfma_f32_16x16x32_bf16(a, b, acc[tn], 0, 0, 0);
        }
    }

    // epilogue: store xw + fused alpha (wave owns heads {2ch, 2ch+1})
    int rbase = row0 + quad * 4;
#pragma unroll
    for (int tn = 0; tn < 8; ++tn) {
        int c = ch * 128 + tn * 16 + l15;
#pragma unroll
        for (int i = 0; i < 4; ++i) {
            int r = rbase + i;
            if (r < N) xw[(size_t)r * 256 + c] = f2bf(acc[tn][i]);
        }
    }
    float ss[2][4] = {{0.f,0.f,0.f,0.f},{0.f,0.f,0.f,0.f}};
    float dd[2][4] = {{0.f,0.f,0.f,0.f},{0.f,0.f,0.f,0.f}};
#pragma unroll
    for (int tn = 0; tn < 8; ++tn) {
        int c = ch * 128 + tn * 16 + l15;
        float sv = asf[c], dv = adf[c];
        int hs = tn >> 2;
#pragma unroll
        for (int i = 0; i < 4; ++i) {
            ss[hs][i] += acc[tn][i] * sv;
            dd[hs][i] += acc[tn][i] * dv;
        }
    }
#pragma unroll
    for (int hs = 0; hs < 2; ++hs)
#pragma unroll
        for (int i = 0; i < 4; ++i) {
            float s = ss[hs][i], d = dd[hs][i];
            s += __shfl_xor(s, 1); d += __shfl_xor(d, 1);
            s += __shfl_xor(s, 2); d += __shfl_xor(d, 2);
            s += __shfl_xor(s, 4); d += __shfl_xor(d, 4);
            s += __shfl_xor(s, 8); d += __shfl_xor(d, 8);
            ss[hs][i] = s; dd[hs][i] = d;
        }
    if (l15 == 0) {
#pragma unroll
        for (int hs = 0; hs < 2; ++hs)
#pragma unroll
            for (int i = 0; i < 4; ++i) {
                int r = rbase + i;
                if (r < N) {
                    int g = r * 4 + ch * 2 + hs;
                    as_[g] = ss[hs][i];
                    ad_[g] = dd[hs][i];
                }
            }
    }
}

__device__ __forceinline__ float leaky(float v) { return v > 0.f ? v : 0.2f * v; }

// ---------- K5: CSR online-softmax aggregate -> z' fp16 (bias folded) ----------
// v2: 2 edges per wave-iteration. Lanes 0-31 take edge j (16B/lane covers the
// 512B row), lanes 32-63 take edge j+1. Online-softmax state kept consistent
// across halves via one shfl_xor(e,32) per iteration (both halves rescale by
// the same c); per-half partial (a,l) merged once at the end. Self term is
// initialized in the lo half only. Halves load instructions, addressing VALU,
// and per-wave chain length vs the 8B/lane one-edge version.
__global__ void agg_csr(const unsigned short* __restrict__ csr, const int* __restrict__ rs,
                        const float* __restrict__ as_, const float* __restrict__ ad_,
                        const unsigned short* __restrict__ xw,
                        const float* __restrict__ biasf,
                        _Float16* __restrict__ zb, int N, int p) {
    int d = blockIdx.x * 4 + (threadIdx.x >> 6);
    if (d >= N) return;
    int lane = threadIdx.x & 63;
    int half = lane >> 5;                 // 0: even edges, 1: odd edges
    int l31  = lane & 31;
    int col8 = l31 * 8;                   // 8 contiguous cols per lane (same head)
    int h    = col8 >> 6;
    int seg = p * N + d;
    int start = rs[seg], end = rs[seg + 1];

    float adh = ad_[d * 4 + h];
    float m = leaky(as_[d * 4 + h] + adh);   // identical in both halves
    float l = (half == 0) ? 1.f : 0.f;       // self term in lo half only
    float a[8];
    {
        u16x8 u = *reinterpret_cast<const u16x8*>(xw + (size_t)d * 256 + col8);
#pragma unroll
        for (int k = 0; k < 8; ++k) a[k] = (half == 0) ? bf2f(u[k]) : 0.f;
    }

    if (start < end) {
        // prologue: this half's first edge (clamped index, gated score)
        int i0 = min(start + half, end - 1);
        int srcA = csr[i0];
        float eA = (start + half < end) ? leaky(as_[srcA * 4 + h] + adh) : -1e30f;
        u16x8 xA = *reinterpret_cast<const u16x8*>(xw + (size_t)srcA * 256 + col8);
        for (int jb = start; jb < end; jb += 2) {
            // issue next pair's loads before this pair's math
            int nidx = jb + 2 + half;
            int ni = min(nidx, end - 1);
            int srcB = csr[ni];
            float eB = (nidx < end) ? leaky(as_[srcB * 4 + h] + adh) : -1e30f;
            u16x8 xB = *reinterpret_cast<const u16x8*>(xw + (size_t)srcB * 256 + col8);
            // joint online-softmax update (both halves same m, same c)
            float eO = __shfl_xor(eA, 32);
            float mn = fmaxf(m, fmaxf(eA, eO));
            float c  = __expf(m - mn);
            float w  = __expf(eA - mn);
            m = mn;
            l = l * c + w;
#pragma unroll
            for (int k = 0; k < 8; ++k)
                a[k] = a[k] * c + w * bf2f(xA[k]);
            srcA = srcB; eA = eB; xA = xB;
        }
    }
    // merge halves (both halves share the same final m)
    l += __shfl_xor(l, 32);
#pragma unroll
    for (int k = 0; k < 8; ++k) a[k] += __shfl_xor(a[k], 32);

    if (half == 0) {
        float inv = 1.f / l;
        const float* bp = biasf + p * 256 + col8;
        f16x8 o;
#pragma unroll
        for (int k = 0; k < 8; ++k) o[k] = (_Float16)(a[k] * inv + bp[k]);
        *reinterpret_cast<f16x8*>(zb + ((size_t)d * 3 + p) * 256 + col8) = o;
    }
}

// ---------- K6: semantic attention (f16 MFMA, w1 in swizzled LDS) ----------
// 1024-thread blocks (16 waves, 16 rows/wave): 64 KB w1 tile serves 16 waves,
// 2 blocks/CU -> 32 waves/CU.
__global__ __launch_bounds__(1024, 4)
void sem_w_mfma(const _Float16* __restrict__ zb,
                const _Float16* __restrict__ w1t,   // [128 n][256 k] f16
                const float* __restrict__ b1f,
                const float* __restrict__ w2f,
                float* __restrict__ wsum, int rows) {
    __shared__ _Float16 Bs[32768];      // 64 KB, 16B-chunk XOR swizzle
    __shared__ float redbuf[16][3];     // per-wave bins for block reduction
    int tid = threadIdx.x;
    {
        const f16x8* src = (const f16x8*)w1t;
#pragma unroll
        for (int it = 0; it < 4; ++it) {
            int c = it * 1024 + tid;
            int row = c >> 5, cv = c & 31;
            *(f16x8*)(Bs + ((row << 5) + (cv ^ (row & 7))) * 8) = src[c];
        }
    }
    __syncthreads();

    int wave = tid >> 6, lane = tid & 63;
    int l15 = lane & 15, quad = lane >> 4;
    int sw  = l15 & 7;
    int row0 = blockIdx.x * 256 + wave * 16;
    int lr = min(row0 + l15, rows - 1);

    f32x4 acc[8];
#pragma unroll
    for (int tn = 0; tn < 8; ++tn) acc[tn] = (f32x4){0.f, 0.f, 0.f, 0.f};

#pragma unroll
    for (int c0 = 0; c0 < 32; c0 += 4) {
        int kc = c0 * 8;
        f16x8 a = *reinterpret_cast<const f16x8*>(zb + (size_t)lr * 256 + kc + quad * 8);
#pragma unroll
        for (int tn = 0; tn < 8; ++tn) {
            int brow = tn * 16 + l15;
            f16x8 b = *reinterpret_cast<const f16x8*>(
                Bs + ((brow << 5) + ((c0 + quad) ^ sw)) * 8);
            acc[tn] = __builtin_amdgcn_mfma_f32_16x16x32_f16(a, b, acc[tn], 0, 0, 0);
        }
    }

    // epilogue: per-row tanh-dot, reduce over hidden (l15), bin by row%3
    float rowsum[4] = {0.f, 0.f, 0.f, 0.f};
#pragma unroll
    for (int tn = 0; tn < 8; ++tn) {
        int col = tn * 16 + l15;
        float b1v = b1f[col], w2v = w2f[col];
#pragma unroll
        for (int i = 0; i < 4; ++i)
            rowsum[i] += fast_tanh(acc[tn][i] + b1v) * w2v;
    }
#pragma unroll
    for (int i = 0; i < 4; ++i) {
        rowsum[i] += __shfl_xor(rowsum[i], 1);
        rowsum[i] += __shfl_xor(rowsum[i], 2);
        rowsum[i] += __shfl_xor(rowsum[i], 4);
        rowsum[i] += __shfl_xor(rowsum[i], 8);
    }
    float bins[3] = {0.f, 0.f, 0.f};
    if (l15 == 0) {
#pragma unroll
        for (int i = 0; i < 4; ++i) {
            int r = row0 + quad * 4 + i;
            if (r < rows) bins[r % 3] += rowsum[i];
        }
    }
#pragma unroll
    for (int b = 0; b < 3; ++b) {   // combine the 4 quads (lanes 0,16,32,48)
        bins[b] += __shfl_xor(bins[b], 16);
        bins[b] += __shfl_xor(bins[b], 32);
    }
    if (lane == 0) {
#pragma unroll
        for (int b = 0; b < 3; ++b) redbuf[wave][b] = bins[b];
    }
    __syncthreads();
    if (tid < 3) {                  // block-level reduce: 3 atomics per block
        float s = 0.f;
#pragma unroll
        for (int w = 0; w < 16; ++w) s += redbuf[w][tid];
        atomicAdd(&wsum[tid], s);
    }
}

// ---------- K8: combine with fused beta = softmax(mean) ----------
__global__ void combine(const _Float16* __restrict__ zb,
                        const float* __restrict__ wsum, float invN,
                        void* __restrict__ out, const int* __restrict__ flags) {
    int idx = blockIdx.x * 256 + threadIdx.x;    // over N*64
    int n = idx >> 6, c4 = (idx & 63) * 4;
    float w0 = wsum[0] * invN, w1 = wsum[1] * invN, w2 = wsum[2] * invN;
    float mx = fmaxf(w0, fmaxf(w1, w2));
    float e0 = __expf(w0 - mx), e1 = __expf(w1 - mx), e2 = __expf(w2 - mx);
    float s = 1.f / (e0 + e1 + e2);
    float b0 = e0 * s, b1 = e1 * s, b2 = e2 * s;
    const _Float16* base = zb + (size_t)n * 768 + c4;
    f16x4 z0 = *reinterpret_cast<const f16x4*>(base);
    f16x4 z1 = *reinterpret_cast<const f16x4*>(base + 256);
    f16x4 z2 = *reinterpret_cast<const f16x4*>(base + 512);
    float v[4];
#pragma unroll
    for (int i = 0; i < 4; ++i)
        v[i] = b0 * (float)z0[i] + b1 * (float)z1[i] + b2 * (float)z2[i];
    if (flags[0]) {
        ushort4 o = {f2bf(v[0]), f2bf(v[1]), f2bf(v[2]), f2bf(v[3])};
        *reinterpret_cast<ushort4*>((unsigned short*)out + (size_t)idx * 4) = o;
    } else {
        f32x4 o = {v[0], v[1], v[2], v[3]};
        *reinterpret_cast<f32x4*>((float*)out + (size_t)idx * 4) = o;
    }
}

extern "C" void kernel_launch(void* const* d_in, const int* in_sizes, int n_in,
                              void* d_out, int out_size, void* d_ws, size_t ws_size,
                              hipStream_t stream) {
    const void* h    = d_in[0];
    const void* e0   = d_in[1];
    const void* e1   = d_in[2];
    const void* e2   = d_in[3];
    const void* W    = d_in[4];
    const void* as   = d_in[5];
    const void* ad   = d_in[6];
    const void* bias = d_in[7];
    const void* w1   = d_in[8];
    const void* b1   = d_in[9];
    const void* w2   = d_in[10];

    const int N = in_sizes[0] / 256;   // 50000
    const int E = in_sizes[1] / 2;     // 400000
    const int M = 3 * N;               // 150000 segments
    const int NB = (M + 1023) >> 10;   // 147 coarse buckets

    char* ws = (char*)d_ws;
    unsigned short* xw    = (unsigned short*)(ws + XW_OFF);
    _Float16*       zb    = (_Float16*)(ws + ZB_OFF);
    unsigned short* csr   = (unsigned short*)(ws + CSR_OFF);
    int*            rs    = (int*)(ws + RS_OFF);
    unsigned short* Wt    = (unsigned short*)(ws + WT_OFF);
    _Float16*       w1t   = (_Float16*)(ws + W1T_OFF);
    float*          asf   = (float*)(ws + ASF_OFF);
    float*          adf   = (float*)(ws + ADF_OFF);
    float*          biasf = (float*)(ws + BIASF_OFF);
    float*          b1f   = (float*)(ws + B1F_OFF);
    float*          w2f   = (float*)(ws + W2F_OFF);
    float*          wsum  = (float*)(ws + WSUM_OFF);
    float*          as_   = (float*)(ws + AS_OFF);
    float*          ad_   = (float*)(ws + AD_OFF);
    int*            flags = (int*)(ws + FLAG_OFF);

    // bucket-sort scratch overlays the zb region (dead until agg_csr)
    unsigned int* bkt  = (unsigned int*)(ws + ZB_OFF);                 // NB*CAPB u32 = 9.6 MB
    int*          bcnt = (int*)(ws + ZB_OFF + (size_t)NBMAX * CAPB * 4);  // NBMAX ints

    probe<<<1, 64, 0, stream>>>((const unsigned short*)h, (const unsigned int*)e0, flags);
    ingest_params<<<907, 256, 0, stream>>>(W, as, ad, bias, w1, b1, w2,
                                           Wt, w1t, asf, adf, biasf, b1f, w2f, flags);

    // CSR build v4: two-pass LDS counting sort (replaces hist+scan+scatter)
    hipMemsetAsync(bcnt, 0, NBMAX * sizeof(int), stream);
    int aBlocks = (3 * E + CHUNKA - 1) / CHUNKA;   // 240
    bucket_a<<<aBlocks, 256, 0, stream>>>(e0, e1, e2, bcnt, bkt, E, N, NB, flags);
    bucket_b<<<NB, 256, 0, stream>>>(bcnt, bkt, rs, csr, M, NB, 3 * E);

    hipMemsetAsync(wsum, 0, 16, stream);

    int gemmBlocks = ((N + 255) / 256) * 2;        // 392
    int aggBlocks  = (N + 3) / 4;                  // 12500
    for (int p = 0; p < 3; ++p) {
        gemm_xw_mfma<<<gemmBlocks, 1024, 0, stream>>>(h, Wt + p * 65536, xw,
                                                      asf + p * 256, adf + p * 256,
                                                      as_, ad_, flags, N);
        agg_csr<<<aggBlocks, 256, 0, stream>>>(csr, rs, as_, ad_, xw, biasf, zb, N, p);
    }

    int semBlocks = (M + 255) / 256;               // 586
    sem_w_mfma<<<semBlocks, 1024, 0, stream>>>(zb, w1t, b1f, w2f, wsum, M);
    combine<<<(N * 64 + 255) / 256, 256, 0, stream>>>(zb, wsum, 1.0f / (float)N, d_out, flags);
}

// Round 9
// 442.520 us; speedup vs baseline: 1.2390x; 1.0020x over previous
//
#include <hip/hip_runtime.h>
#include <hip/hip_bf16.h>

// ---------- helpers ----------
__device__ __forceinline__ float bf2f(unsigned short u) {
    union { unsigned int i; float f; } x;
    x.i = ((unsigned int)u) << 16;
    return x.f;
}
__device__ __forceinline__ unsigned short f2bf(float f) {
    union { float f; unsigned int u; } x; x.f = f;
    unsigned int r = x.u + 0x7FFFu + ((x.u >> 16) & 1u);
    return (unsigned short)(r >> 16);
}
__device__ __forceinline__ float fast_tanh(float x) {
    float a = fabsf(x);
    float t = __expf(2.f * a);
    float r = 1.f - 2.f / (t + 1.f);
    return copysignf(r, x);
}

typedef __bf16    bf16x8 __attribute__((ext_vector_type(8)));
typedef _Float16  f16x8  __attribute__((ext_vector_type(8)));
typedef _Float16  f16x4  __attribute__((ext_vector_type(4)));
typedef float     f32x4  __attribute__((ext_vector_type(4)));
typedef unsigned short u16x8 __attribute__((ext_vector_type(8)));

// ---------- workspace byte offsets (total ~110.5 MB) ----------
#define XW_OFF     0UL            // N*256 bf16      = 25,600,000
#define ZB_OFF     25600000UL     // 3N*256 f16      = 76,800,000 (bias folded)
                                  // (bucket-sort scratch reuses this region
                                  //  before agg_csr writes zb)
#define CSR_OFF    102400000UL    // 3E u16          =  2,400,000
#define RS_OFF     107200000UL    // (3N+1) int32
#define CUR_OFF    107800064UL    // 3N int32 (unused now)
#define BS_OFF     108400128UL    // 256 int32 (unused now)
#define AS_OFF     108401152UL    // N*4 f32
#define AD_OFF     109201152UL    // N*4 f32
#define WT_OFF     110001152UL    // 3*256*256 bf16 (transposed W)
#define W1T_OFF    110394368UL    // 128*256 f16 (transposed w1)
#define ASF_OFF    110459904UL    // 768 f32
#define ADF_OFF    110462976UL
#define BIASF_OFF  110466048UL
#define B1F_OFF    110469120UL
#define W2F_OFF    110469632UL
#define WSUM_OFF   110470144UL
#define BETA_OFF   110470208UL
#define FLAG_OFF   110470272UL

// ---------- CSR-build v4 constants ----------
#define CHUNKA 5000     // edges per bucket_a block
#define NBMAX  152      // >= NB = ceil(3N/1024) = 147 ; must be <= 255 (u8)
#define CAPB   16384    // per-bucket capacity (mean 8163, +90 sigma)

// ---------- P0: dtype probe ----------
__global__ void probe(const unsigned short* __restrict__ hraw,
                      const unsigned int* __restrict__ eraw,
                      int* __restrict__ flags) {
    if (threadIdx.x == 0 && blockIdx.x == 0) {
        int sane = 0;
        for (int i = 0; i < 256; ++i) {
            unsigned int e = (hraw[i] >> 7) & 0xFF;
            if (hraw[i] != 0 && e >= 100 && e <= 150) sane++;
        }
        flags[0] = (sane >= 220) ? 1 : 0;   // 1 = bf16 inputs/outputs
        int zeros = 0;
        for (int i = 1; i < 256; i += 2) if (eraw[i] == 0u) zeros++;
        flags[1] = (zeros >= 120) ? 1 : 0;  // 1 = int64 indices
    }
}

__device__ __forceinline__ float rd_f(const void* p, int j, bool bf) {
    return bf ? bf2f(((const unsigned short*)p)[j]) : ((const float*)p)[j];
}
__device__ __forceinline__ int rd_i(const void* p, long long j, bool i64) {
    return i64 ? (int)((const long long*)p)[j] : ((const int*)p)[j];
}

// ---------- P1: canonicalize params ----------
__global__ void ingest_params(const void* W, const void* as, const void* ad, const void* bias,
                              const void* w1, const void* b1, const void* w2,
                              unsigned short* Wt, _Float16* w1t,
                              float* asf, float* adf, float* biasf,
                              float* b1f, float* w2f,
                              const int* __restrict__ flags) {
    int i = blockIdx.x * 256 + threadIdx.x;
    bool bf = flags[0] != 0;
    if (i < 196608) {                              // Wt[p][n][k] = W[p][k][n]
        int p = i >> 16, n = (i >> 8) & 255, k = i & 255;
        Wt[i] = f2bf(rd_f(W, p * 65536 + k * 256 + n, bf));
    } else if (i < 229376) {                       // w1t[n][k] = w1[k][n], fp16
        int j = i - 196608;
        int n = j >> 8, k = j & 255;
        w1t[j] = (_Float16)rd_f(w1, k * 128 + n, bf);
    } else if (i < 230144) {
        int j = i - 229376; asf[j] = rd_f(as, j, bf);
    } else if (i < 230912) {
        int j = i - 230144; adf[j] = rd_f(ad, j, bf);
    } else if (i < 231680) {
        int j = i - 230912; biasf[j] = rd_f(bias, j, bf);
    } else if (i < 231808) {
        int j = i - 231680; b1f[j] = rd_f(b1, j, bf);
    } else if (i < 231936) {
        int j = i - 231808; w2f[j] = rd_f(w2, j, bf);
    }
}

// ---------- CSR build v4: LDS-staged two-pass counting sort ----------
__global__ __launch_bounds__(256)
void bucket_a(const void* e0, const void* e1, const void* e2,
              int* __restrict__ bcnt, unsigned int* __restrict__ bkt,
              int E, int N, int NB, const int* __restrict__ flags) {
    __shared__ unsigned int  ent[CHUNKA];
    __shared__ unsigned char bck[CHUNKA];
    __shared__ unsigned int  sent[CHUNKA];
    __shared__ unsigned char sbck[CHUNKA];
    __shared__ int lcnt[NBMAX], lpre[NBMAX], lbase[NBMAX], lcur[NBMAX];
    int tid = threadIdx.x;
    int s = blockIdx.x * CHUNKA;
    int tot = 3 * E;
    int n = min(tot, s + CHUNKA) - s;
    for (int b = tid; b < NBMAX; b += 256) { lcnt[b] = 0; lcur[b] = 0; }
    __syncthreads();
    bool i64 = flags[1] != 0;
    for (int i = tid; i < n; i += 256) {
        int idx = s + i;
        int p = (idx >= 2 * E) ? 2 : (idx >= E) ? 1 : 0;
        int j = idx - p * E;
        const void* ep = (p == 0) ? e0 : (p == 1) ? e1 : e2;
        unsigned int src = (unsigned int)rd_i(ep, j, i64);
        unsigned int dst = (unsigned int)rd_i(ep, (long long)E + j, i64);
        int seg = p * N + (int)dst;
        int b = seg >> 10;
        ent[i] = src | ((unsigned int)(seg & 1023) << 16);
        bck[i] = (unsigned char)b;
        atomicAdd(&lcnt[b], 1);
    }
    __syncthreads();
    if (tid == 0) {                       // block-local exclusive prefix (147 iters)
        int run = 0;
        for (int b = 0; b < NB; ++b) { lpre[b] = run; run += lcnt[b]; }
    }
    if (tid < NB) lbase[tid] = atomicAdd(&bcnt[tid], lcnt[tid]);   // global reserve
    __syncthreads();
    for (int i = tid; i < n; i += 256) {  // LDS counting-sort placement
        int b = bck[i];
        int pos = lpre[b] + atomicAdd(&lcur[b], 1);
        sent[pos] = ent[i];
        sbck[pos] = (unsigned char)b;
    }
    __syncthreads();
    for (int q = tid; q < n; q += 256) {  // coalesced run write-out
        int b = sbck[q];
        int gpos = lbase[b] + (q - lpre[b]);
        if (gpos < CAPB) bkt[(size_t)b * CAPB + gpos] = sent[q];
    }
}

// bucket_b: per bucket, LDS per-seg histogram + prefix -> writes rs directly
// and places edges into its contiguous csr region (full-line writebacks).
__global__ __launch_bounds__(256)
void bucket_b(const int* __restrict__ bcnt, const unsigned int* __restrict__ bkt,
              int* __restrict__ rs, unsigned short* __restrict__ csr,
              int M, int NB, int tot) {
    __shared__ int scnt[1024];
    __shared__ int spre[1024];
    __shared__ int part[256];
    int b = blockIdx.x, tid = threadIdx.x;
    // base = prefix sum of bcnt[0..b)
    int acc = 0;
    for (int i = tid; i < b; i += 256) acc += min(bcnt[i], CAPB);
    part[tid] = acc; __syncthreads();
    for (int o = 128; o > 0; o >>= 1) {
        if (tid < o) part[tid] += part[tid + o];
        __syncthreads();
    }
    int base = part[0];
    int cnt = min(bcnt[b], CAPB);
    for (int i = tid; i < 1024; i += 256) scnt[i] = 0;
    __syncthreads();
    const unsigned int* src = bkt + (size_t)b * CAPB;
    for (int i = tid; i < cnt; i += 256)
        atomicAdd(&scnt[src[i] >> 16], 1);
    __syncthreads();
    // exclusive prefix over 1024 counters (4 items/thread + block scan)
    int a0 = scnt[tid * 4], a1 = scnt[tid * 4 + 1], a2 = scnt[tid * 4 + 2], a3 = scnt[tid * 4 + 3];
    int psum = a0 + a1 + a2 + a3;
    part[tid] = psum; __syncthreads();
    for (int o = 1; o < 256; o <<= 1) {
        int tmp = (tid >= o) ? part[tid - o] : 0;
        __syncthreads();
        part[tid] += tmp;
        __syncthreads();
    }
    int pb = part[tid] - psum;
    spre[tid * 4]     = pb;
    spre[tid * 4 + 1] = pb + a0;
    spre[tid * 4 + 2] = pb + a0 + a1;
    spre[tid * 4 + 3] = pb + a0 + a1 + a2;
    __syncthreads();
    // write rs for this bucket's segments; reset cursors
    for (int i = tid; i < 1024; i += 256) {
        int seg = b * 1024 + i;
        if (seg < M) rs[seg] = base + spre[i];
        scnt[i] = 0;
    }
    if (b == NB - 1 && tid == 0) rs[M] = tot;
    __syncthreads();
    // place (random within single-owner 16KB region -> full-line writebacks)
    for (int i = tid; i < cnt; i += 256) {
        unsigned int u = src[i];
        int slow = u >> 16;
        int pos = spre[slow] + atomicAdd(&scnt[slow], 1);
        csr[base + pos] = (unsigned short)(u & 0xFFFFu);
    }
}

// ---------- K1: xw = h @ W[p] (MFMA, B in swizzled LDS) ----------
// v3: 1024-thread blocks (16 waves, 16 rows/wave) + full-row register preload
// (8 h-loads in flight/wave, restores the ILP lost in the rt=4->1 change) +
// XCD pair-swizzle so blocks 2g/2g+1 (same h rows, different col half) land on
// the same XCD -> second gets L2 hits on h.
__global__ __launch_bounds__(1024, 4)
void gemm_xw_mfma(const void* __restrict__ h,
                  const unsigned short* __restrict__ Wtp,   // [256 n][256 k] bf16
                  unsigned short* __restrict__ xw,
                  const float* __restrict__ asf,            // [256] this path
                  const float* __restrict__ adf,
                  float* __restrict__ as_, float* __restrict__ ad_,
                  const int* __restrict__ flags, int N) {
    __shared__ __bf16 Bs[32768];        // 64 KB: 128 rows x 256 k, 16B-chunk XOR swizzle
    int tid  = threadIdx.x;
    // XCD pair-swizzle: gridDim.x is a multiple of 8 (392 = 8*49)
    int D = blockIdx.x;
    int qch = gridDim.x >> 3;
    int logical = (D & 7) * qch + (D >> 3);
    int ch   = logical & 1;             // col half
    int rg   = logical >> 1;            // row group (256 rows)
    // stage B half into LDS (chunk c of row r -> slot c ^ (r&7))
    {
        const bf16x8* src = (const bf16x8*)Wtp;
#pragma unroll
        for (int it = 0; it < 4; ++it) {
            int c = it * 1024 + tid;
            int row = c >> 5, cv = c & 31;
            *(bf16x8*)(Bs + ((row << 5) + (cv ^ (row & 7))) * 8) =
                src[(ch * 128 + row) * 32 + cv];
        }
    }
    __syncthreads();

    int wave = tid >> 6, lane = tid & 63;
    int l15 = lane & 15, quad = lane >> 4;
    int sw  = l15 & 7;
    int row0 = rg * 256 + wave * 16;
    bool bfm = flags[0] != 0;

    int lr = min(row0 + l15, N - 1);

    // preload the lane's full 128 B of h (8 chunks, all in flight)
    bf16x8 a[8];
    if (bfm) {
        const bf16x8* hp = reinterpret_cast<const bf16x8*>((const __bf16*)h + (size_t)lr * 256);
#pragma unroll
        for (int t = 0; t < 8; ++t) a[t] = hp[t * 4 + quad];
    } else {
        const float* hp = (const float*)h + (size_t)lr * 256;
#pragma unroll
        for (int t = 0; t < 8; ++t) {
            int off = t * 32 + quad * 8;
            f32x4 u0 = *reinterpret_cast<const f32x4*>(hp + off);
            f32x4 u1 = *reinterpret_cast<const f32x4*>(hp + off + 4);
#pragma unroll
            for (int j = 0; j < 4; ++j) { a[t][j] = (__bf16)u0[j]; a[t][4 + j] = (__bf16)u1[j]; }
        }
    }

    f32x4 acc[8];
#pragma unroll
    for (int tn = 0; tn < 8; ++tn) acc[tn] = (f32x4){0.f, 0.f, 0.f, 0.f};

#pragma unroll
    for (int t = 0; t < 8; ++t) {
        int c0 = t * 4;
#pragma unroll
        for (int tn = 0; tn < 8; ++tn) {
            int row = tn * 16 + l15;
            bf16x8 b = *reinterpret_cast<const bf16x8*>(
                Bs + ((row << 5) + ((c0 + quad) ^ sw)) * 8);
            acc[tn] = __builtin_amdgcn_mfma_f32_16x16x32_bf16(a[t], b, acc[tn], 0, 0, 0);
        }
    }

    // epilogue: store xw + fused alpha (wave owns heads {2ch, 2ch+1})
    int rbase = row0 + quad * 4;
#pragma unroll
    for (int tn = 0; tn < 8; ++tn) {
        int c = ch * 128 + tn * 16 + l15;
#pragma unroll
        for (int i = 0; i < 4; ++i) {
            int r = rbase + i;
            if (r < N) xw[(size_t)r * 256 + c] = f2bf(acc[tn][i]);
        }
    }
    float ss[2][4] = {{0.f,0.f,0.f,0.f},{0.f,0.f,0.f,0.f}};
    float dd[2][4] = {{0.f,0.f,0.f,0.f},{0.f,0.f,0.f,0.f}};
#pragma unroll
    for (int tn = 0; tn < 8; ++tn) {
        int c = ch * 128 + tn * 16 + l15;
        float sv = asf[c], dv = adf[c];
        int hs = tn >> 2;
#pragma unroll
        for (int i = 0; i < 4; ++i) {
            ss[hs][i] += acc[tn][i] * sv;
            dd[hs][i] += acc[tn][i] * dv;
        }
    }
#pragma unroll
    for (int hs = 0; hs < 2; ++hs)
#pragma unroll
        for (int i = 0; i < 4; ++i) {
            float s = ss[hs][i], d = dd[hs][i];
            s += __shfl_xor(s, 1); d += __shfl_xor(d, 1);
            s += __shfl_xor(s, 2); d += __shfl_xor(d, 2);
            s += __shfl_xor(s, 4); d += __shfl_xor(d, 4);
            s += __shfl_xor(s, 8); d += __shfl_xor(d, 8);
            ss[hs][i] = s; dd[hs][i] = d;
        }
    if (l15 == 0) {
#pragma unroll
        for (int hs = 0; hs < 2; ++hs)
#pragma unroll
            for (int i = 0; i < 4; ++i) {
                int r = rbase + i;
                if (r < N) {
                    int g = r * 4 + ch * 2 + hs;
                    as_[g] = ss[hs][i];
                    ad_[g] = dd[hs][i];
                }
            }
    }
}

__device__ __forceinline__ float leaky(float v) { return v > 0.f ? v : 0.2f * v; }

// ---------- K5: CSR online-softmax aggregate -> z' fp16 (bias folded) ----------
// 2 edges per wave-iteration; at the measured memory-system floor (R5/R8).
__global__ void agg_csr(const unsigned short* __restrict__ csr, const int* __restrict__ rs,
                        const float* __restrict__ as_, const float* __restrict__ ad_,
                        const unsigned short* __restrict__ xw,
                        const float* __restrict__ biasf,
                        _Float16* __restrict__ zb, int N, int p) {
    int d = blockIdx.x * 4 + (threadIdx.x >> 6);
    if (d >= N) return;
    int lane = threadIdx.x & 63;
    int half = lane >> 5;                 // 0: even edges, 1: odd edges
    int l31  = lane & 31;
    int col8 = l31 * 8;                   // 8 contiguous cols per lane (same head)
    int h    = col8 >> 6;
    int seg = p * N + d;
    int start = rs[seg], end = rs[seg + 1];

    float adh = ad_[d * 4 + h];
    float m = leaky(as_[d * 4 + h] + adh);   // identical in both halves
    float l = (half == 0) ? 1.f : 0.f;       // self term in lo half only
    float a[8];
    {
        u16x8 u = *reinterpret_cast<const u16x8*>(xw + (size_t)d * 256 + col8);
#pragma unroll
        for (int k = 0; k < 8; ++k) a[k] = (half == 0) ? bf2f(u[k]) : 0.f;
    }

    if (start < end) {
        int i0 = min(start + half, end - 1);
        int srcA = csr[i0];
        float eA = (start + half < end) ? leaky(as_[srcA * 4 + h] + adh) : -1e30f;
        u16x8 xA = *reinterpret_cast<const u16x8*>(xw + (size_t)srcA * 256 + col8);
        for (int jb = start; jb < end; jb += 2) {
            int nidx = jb + 2 + half;
            int ni = min(nidx, end - 1);
            int srcB = csr[ni];
            float eB = (nidx < end) ? leaky(as_[srcB * 4 + h] + adh) : -1e30f;
            u16x8 xB = *reinterpret_cast<const u16x8*>(xw + (size_t)srcB * 256 + col8);
            float eO = __shfl_xor(eA, 32);
            float mn = fmaxf(m, fmaxf(eA, eO));
            float c  = __expf(m - mn);
            float w  = __expf(eA - mn);
            m = mn;
            l = l * c + w;
#pragma unroll
            for (int k = 0; k < 8; ++k)
                a[k] = a[k] * c + w * bf2f(xA[k]);
            srcA = srcB; eA = eB; xA = xB;
        }
    }
    l += __shfl_xor(l, 32);
#pragma unroll
    for (int k = 0; k < 8; ++k) a[k] += __shfl_xor(a[k], 32);

    if (half == 0) {
        float inv = 1.f / l;
        const float* bp = biasf + p * 256 + col8;
        f16x8 o;
#pragma unroll
        for (int k = 0; k < 8; ++k) o[k] = (_Float16)(a[k] * inv + bp[k]);
        *reinterpret_cast<f16x8*>(zb + ((size_t)d * 3 + p) * 256 + col8) = o;
    }
}

// ---------- K6: semantic attention (f16 MFMA, w1 in swizzled LDS) ----------
// 1024-thread blocks (16 waves, 16 rows/wave) + full-row register preload.
__global__ __launch_bounds__(1024, 4)
void sem_w_mfma(const _Float16* __restrict__ zb,
                const _Float16* __restrict__ w1t,   // [128 n][256 k] f16
                const float* __restrict__ b1f,
                const float* __restrict__ w2f,
                float* __restrict__ wsum, int rows) {
    __shared__ _Float16 Bs[32768];      // 64 KB, 16B-chunk XOR swizzle
    __shared__ float redbuf[16][3];     // per-wave bins for block reduction
    int tid = threadIdx.x;
    {
        const f16x8* src = (const f16x8*)w1t;
#pragma unroll
        for (int it = 0; it < 4; ++it) {
            int c = it * 1024 + tid;
            int row = c >> 5, cv = c & 31;
            *(f16x8*)(Bs + ((row << 5) + (cv ^ (row & 7))) * 8) = src[c];
        }
    }
    __syncthreads();

    int wave = tid >> 6, lane = tid & 63;
    int l15 = lane & 15, quad = lane >> 4;
    int sw  = l15 & 7;
    int row0 = blockIdx.x * 256 + wave * 16;
    int lr = min(row0 + l15, rows - 1);

    // preload the lane's full 128 B of zb (8 chunks in flight)
    f16x8 a[8];
    {
        const f16x8* zp = reinterpret_cast<const f16x8*>(zb + (size_t)lr * 256);
#pragma unroll
        for (int t = 0; t < 8; ++t) a[t] = zp[t * 4 + quad];
    }

    f32x4 acc[8];
#pragma unroll
    for (int tn = 0; tn < 8; ++tn) acc[tn] = (f32x4){0.f, 0.f, 0.f, 0.f};

#pragma unroll
    for (int t = 0; t < 8; ++t) {
        int c0 = t * 4;
#pragma unroll
        for (int tn = 0; tn < 8; ++tn) {
            int brow = tn * 16 + l15;
            f16x8 b = *reinterpret_cast<const f16x8*>(
                Bs + ((brow << 5) + ((c0 + quad) ^ sw)) * 8);
            acc[tn] = __builtin_amdgcn_mfma_f32_16x16x32_f16(a[t], b, acc[tn], 0, 0, 0);
        }
    }

    // epilogue: per-row tanh-dot, reduce over hidden (l15), bin by row%3
    float rowsum[4] = {0.f, 0.f, 0.f, 0.f};
#pragma unroll
    for (int tn = 0; tn < 8; ++tn) {
        int col = tn * 16 + l15;
        float b1v = b1f[col], w2v = w2f[col];
#pragma unroll
        for (int i = 0; i < 4; ++i)
            rowsum[i] += fast_tanh(acc[tn][i] + b1v) * w2v;
    }
#pragma unroll
    for (int i = 0; i < 4; ++i) {
        rowsum[i] += __shfl_xor(rowsum[i], 1);
        rowsum[i] += __shfl_xor(rowsum[i], 2);
        rowsum[i] += __shfl_xor(rowsum[i], 4);
        rowsum[i] += __shfl_xor(rowsum[i], 8);
    }
    float bins[3] = {0.f, 0.f, 0.f};
    if (l15 == 0) {
#pragma unroll
        for (int i = 0; i < 4; ++i) {
            int r = row0 + quad * 4 + i;
            if (r < rows) bins[r % 3] += rowsum[i];
        }
    }
#pragma unroll
    for (int b = 0; b < 3; ++b) {   // combine the 4 quads (lanes 0,16,32,48)
        bins[b] += __shfl_xor(bins[b], 16);
        bins[b] += __shfl_xor(bins[b], 32);
    }
    if (lane == 0) {
#pragma unroll
        for (int b = 0; b < 3; ++b) redbuf[wave][b] = bins[b];
    }
    __syncthreads();
    if (tid < 3) {                  // block-level reduce: 3 atomics per block
        float s = 0.f;
#pragma unroll
        for (int w = 0; w < 16; ++w) s += redbuf[w][tid];
        atomicAdd(&wsum[tid], s);
    }
}

// ---------- K8: combine with fused beta = softmax(mean) ----------
__global__ void combine(const _Float16* __restrict__ zb,
                        const float* __restrict__ wsum, float invN,
                        void* __restrict__ out, const int* __restrict__ flags) {
    int idx = blockIdx.x * 256 + threadIdx.x;    // over N*64
    int n = idx >> 6, c4 = (idx & 63) * 4;
    float w0 = wsum[0] * invN, w1 = wsum[1] * invN, w2 = wsum[2] * invN;
    float mx = fmaxf(w0, fmaxf(w1, w2));
    float e0 = __expf(w0 - mx), e1 = __expf(w1 - mx), e2 = __expf(w2 - mx);
    float s = 1.f / (e0 + e1 + e2);
    float b0 = e0 * s, b1 = e1 * s, b2 = e2 * s;
    const _Float16* base = zb + (size_t)n * 768 + c4;
    f16x4 z0 = *reinterpret_cast<const f16x4*>(base);
    f16x4 z1 = *reinterpret_cast<const f16x4*>(base + 256);
    f16x4 z2 = *reinterpret_cast<const f16x4*>(base + 512);
    float v[4];
#pragma unroll
    for (int i = 0; i < 4; ++i)
        v[i] = b0 * (float)z0[i] + b1 * (float)z1[i] + b2 * (float)z2[i];
    if (flags[0]) {
        ushort4 o = {f2bf(v[0]), f2bf(v[1]), f2bf(v[2]), f2bf(v[3])};
        *reinterpret_cast<ushort4*>((unsigned short*)out + (size_t)idx * 4) = o;
    } else {
        f32x4 o = {v[0], v[1], v[2], v[3]};
        *reinterpret_cast<f32x4*>((float*)out + (size_t)idx * 4) = o;
    }
}

extern "C" void kernel_launch(void* const* d_in, const int* in_sizes, int n_in,
                              void* d_out, int out_size, void* d_ws, size_t ws_size,
                              hipStream_t stream) {
    const void* h    = d_in[0];
    const void* e0   = d_in[1];
    const void* e1   = d_in[2];
    const void* e2   = d_in[3];
    const void* W    = d_in[4];
    const void* as   = d_in[5];
    const void* ad   = d_in[6];
    const void* bias = d_in[7];
    const void* w1   = d_in[8];
    const void* b1   = d_in[9];
    const void* w2   = d_in[10];

    const int N = in_sizes[0] / 256;   // 50000
    const int E = in_sizes[1] / 2;     // 400000
    const int M = 3 * N;               // 150000 segments
    const int NB = (M + 1023) >> 10;   // 147 coarse buckets

    char* ws = (char*)d_ws;
    unsigned short* xw    = (unsigned short*)(ws + XW_OFF);
    _Float16*       zb    = (_Float16*)(ws + ZB_OFF);
    unsigned short* csr   = (unsigned short*)(ws + CSR_OFF);
    int*            rs    = (int*)(ws + RS_OFF);
    unsigned short* Wt    = (unsigned short*)(ws + WT_OFF);
    _Float16*       w1t   = (_Float16*)(ws + W1T_OFF);
    float*          asf   = (float*)(ws + ASF_OFF);
    float*          adf   = (float*)(ws + ADF_OFF);
    float*          biasf = (float*)(ws + BIASF_OFF);
    float*          b1f   = (float*)(ws + B1F_OFF);
    float*          w2f   = (float*)(ws + W2F_OFF);
    float*          wsum  = (float*)(ws + WSUM_OFF);
    float*          as_   = (float*)(ws + AS_OFF);
    float*          ad_   = (float*)(ws + AD_OFF);
    int*            flags = (int*)(ws + FLAG_OFF);

    // bucket-sort scratch overlays the zb region (dead until agg_csr)
    unsigned int* bkt  = (unsigned int*)(ws + ZB_OFF);                 // NB*CAPB u32 = 9.6 MB
    int*          bcnt = (int*)(ws + ZB_OFF + (size_t)NBMAX * CAPB * 4);  // NBMAX ints

    probe<<<1, 64, 0, stream>>>((const unsigned short*)h, (const unsigned int*)e0, flags);
    ingest_params<<<907, 256, 0, stream>>>(W, as, ad, bias, w1, b1, w2,
                                           Wt, w1t, asf, adf, biasf, b1f, w2f, flags);

    // CSR build v4: two-pass LDS counting sort (replaces hist+scan+scatter)
    hipMemsetAsync(bcnt, 0, NBMAX * sizeof(int), stream);
    int aBlocks = (3 * E + CHUNKA - 1) / CHUNKA;   // 240
    bucket_a<<<aBlocks, 256, 0, stream>>>(e0, e1, e2, bcnt, bkt, E, N, NB, flags);
    bucket_b<<<NB, 256, 0, stream>>>(bcnt, bkt, rs, csr, M, NB, 3 * E);

    hipMemsetAsync(wsum, 0, 16, stream);

    int gemmBlocks = ((N + 255) / 256) * 2;        // 392 (multiple of 8)
    int aggBlocks  = (N + 3) / 4;                  // 12500
    for (int p = 0; p < 3; ++p) {
        gemm_xw_mfma<<<gemmBlocks, 1024, 0, stream>>>(h, Wt + p * 65536, xw,
                                                      asf + p * 256, adf + p * 256,
                                                      as_, ad_, flags, N);
        agg_csr<<<aggBlocks, 256, 0, stream>>>(csr, rs, as_, ad_, xw, biasf, zb, N, p);
    }

    int semBlocks = (M + 255) / 256;               // 586
    sem_w_mfma<<<semBlocks, 1024, 0, stream>>>(zb, w1t, b1f, w2f, wsum, M);
    combine<<<(N * 64 + 255) / 256, 256, 0, stream>>>(zb, wsum, 1.0f / (float)N, d_out, flags);
}